// Round 1
// baseline (515.887 us; speedup 1.0000x reference)
//
#include <hip/hip_runtime.h>
#include <hip/hip_bf16.h>
#include <stdint.h>

#define K_DIM 4096
#define N_DIM 4096
#define TOKENS 8192
#define GROUPSIZE 128

#define BM 128
#define BN 128
#define BK 64
#define LDS_K (BK + 8)   // 72 bf16 = 144 B row stride (9*16B: keeps b128 align, breaks conflicts)

typedef __attribute__((ext_vector_type(8))) short bf16x8;
typedef __attribute__((ext_vector_type(4))) float f32x4;

__device__ inline unsigned short f2bf(float f) {
    union { float f; unsigned u; } v; v.f = f;
    unsigned r = v.u + 0x7FFF + ((v.u >> 16) & 1);   // RNE
    return (unsigned short)(r >> 16);
}

__global__ __launch_bounds__(256, 2) void q4gemm_kernel(
    const float* __restrict__ x, const int* __restrict__ qweight,
    const int* __restrict__ qzeros, const float* __restrict__ scales,
    const float* __restrict__ bias, float* __restrict__ out)
{
    __shared__ unsigned short As[BM][LDS_K];
    __shared__ unsigned short Bs[BN][LDS_K];

    const int tid  = threadIdx.x;
    const int lane = tid & 63;
    const int wave = tid >> 6;
    const int wr = wave >> 1;       // wave row (0..1) -> 64 rows each
    const int wc = wave & 1;        // wave col (0..1) -> 64 cols each

    const int m0 = blockIdx.x * BM;
    const int n0 = blockIdx.y * BN;

    const int fr = lane & 15;            // fragment row (A-row / B-col)
    const int fq = lane >> 4;            // quad index
    const int kfrag = fq << 3;           // k offset within a 32-wide MFMA K

    f32x4 acc[4][4];
#pragma unroll
    for (int i = 0; i < 4; i++)
#pragma unroll
        for (int j = 0; j < 4; j++) acc[i][j] = (f32x4){0.f, 0.f, 0.f, 0.f};

    for (int k0 = 0; k0 < K_DIM; k0 += BK) {
        const int g = k0 >> 7;   // group index (GROUPSIZE=128, BK=64 never straddles)

        // ---- stage A: 128x64 fp32 -> bf16 LDS.  2048 float4 / 256 thr = 8 each
#pragma unroll
        for (int i = 0; i < 8; i++) {
            int idx = tid + i * 256;
            int row = idx >> 4;
            int c4  = (idx & 15) << 2;
            const float4 v = *reinterpret_cast<const float4*>(
                &x[(size_t)(m0 + row) * K_DIM + k0 + c4]);
            ushort4 h;
            h.x = f2bf(v.x); h.y = f2bf(v.y); h.z = f2bf(v.z); h.w = f2bf(v.w);
            *reinterpret_cast<ushort4*>(&As[row][c4]) = h;
        }

        // ---- stage B: dequant 64x128 -> Bs[n][k].  1024 int32 / 256 thr = 4 each
#pragma unroll
        for (int i = 0; i < 4; i++) {
            int idx = tid + i * 256;
            int krl = idx >> 7;          // 0..7 : which packed qweight row
            int nl  = idx & 127;
            int n   = n0 + nl;
            int q   = qweight[(size_t)(k0 / 8 + krl) * N_DIM + n];
            float sc = scales[(size_t)g * N_DIM + n];
            int zq  = qzeros[(size_t)g * (N_DIM / 8) + (n >> 3)];
            int z   = ((zq >> ((n & 7) * 4)) & 0xF) + 1;
            bf16x8 wv;
#pragma unroll
            for (int s = 0; s < 8; s++) {
                int w = ((q >> (s * 4)) & 0xF) - z;
                wv[s] = (short)f2bf(sc * (float)w);
            }
            *reinterpret_cast<bf16x8*>(&Bs[nl][krl * 8]) = wv;
        }

        __syncthreads();

        // ---- compute: 2 k-steps x 4x4 fragments
        bf16x8 a_frag[2][4], b_frag[2][4];
#pragma unroll
        for (int ks = 0; ks < 2; ks++) {
            const int kb = ks * 32 + kfrag;
#pragma unroll
            for (int mi = 0; mi < 4; mi++)
                a_frag[ks][mi] = *reinterpret_cast<const bf16x8*>(
                    &As[wr * 64 + mi * 16 + fr][kb]);
#pragma unroll
            for (int ni = 0; ni < 4; ni++)
                b_frag[ks][ni] = *reinterpret_cast<const bf16x8*>(
                    &Bs[wc * 64 + ni * 16 + fr][kb]);
        }
#pragma unroll
        for (int ks = 0; ks < 2; ks++)
#pragma unroll
            for (int mi = 0; mi < 4; mi++)
#pragma unroll
                for (int ni = 0; ni < 4; ni++)
                    acc[mi][ni] = __builtin_amdgcn_mfma_f32_16x16x32_bf16(
                        a_frag[ks][mi], b_frag[ks][ni], acc[mi][ni], 0, 0, 0);

        __syncthreads();
    }

    // ---- epilogue: C/D layout col=lane&15, row=(lane>>4)*4+j  (m89-verified)
#pragma unroll
    for (int ni = 0; ni < 4; ni++) {
        const int col = n0 + wc * 64 + ni * 16 + fr;
        const float bv = bias[col];
#pragma unroll
        for (int mi = 0; mi < 4; mi++) {
#pragma unroll
            for (int j = 0; j < 4; j++) {
                const int row = m0 + wr * 64 + mi * 16 + fq * 4 + j;
                out[(size_t)row * N_DIM + col] = acc[mi][ni][j] + bv;
            }
        }
    }
}

extern "C" void kernel_launch(void* const* d_in, const int* in_sizes, int n_in,
                              void* d_out, int out_size, void* d_ws, size_t ws_size,
                              hipStream_t stream) {
    const float* x       = (const float*)d_in[0];
    const int*   qweight = (const int*)d_in[1];
    const int*   qzeros  = (const int*)d_in[2];
    const float* scales  = (const float*)d_in[3];
    // d_in[4] = g_idx: standard layout (k // 128), folded into k0>>7 in-kernel
    const float* bias    = (const float*)d_in[5];
    float*       out     = (float*)d_out;

    dim3 grid(TOKENS / BM, N_DIM / BN);
    q4gemm_kernel<<<grid, dim3(256), 0, stream>>>(x, qweight, qzeros, scales, bias, out);
}

// Round 2
// 359.650 us; speedup vs baseline: 1.4344x; 1.4344x over previous
//
#include <hip/hip_runtime.h>
#include <hip/hip_bf16.h>
#include <stdint.h>

#define K_DIM 4096
#define N_DIM 4096
#define TOKENS 8192
#define GROUPSIZE 128

#define BM 128
#define BN 128
#define BK 64

typedef __attribute__((ext_vector_type(8))) short bf16x8;
typedef __attribute__((ext_vector_type(4))) float f32x4;

__device__ inline unsigned short f2bf(float f) {
    union { float f; unsigned u; } v; v.f = f;
    unsigned r = v.u + 0x7FFF + ((v.u >> 16) & 1);   // RNE
    return (unsigned short)(r >> 16);
}

// ---------------- prepass 1: x fp32 -> bf16 ----------------
__global__ __launch_bounds__(256) void cvt_x_kernel(const float* __restrict__ x,
                                                    unsigned short* __restrict__ xbf)
{
    size_t idx = ((size_t)blockIdx.x * 256 + threadIdx.x) * 8;
    const float4 v0 = *reinterpret_cast<const float4*>(&x[idx]);
    const float4 v1 = *reinterpret_cast<const float4*>(&x[idx + 4]);
    ushort4 h0, h1;
    h0.x = f2bf(v0.x); h0.y = f2bf(v0.y); h0.z = f2bf(v0.z); h0.w = f2bf(v0.w);
    h1.x = f2bf(v1.x); h1.y = f2bf(v1.y); h1.z = f2bf(v1.z); h1.w = f2bf(v1.w);
    *reinterpret_cast<ushort4*>(&xbf[idx]) = h0;
    *reinterpret_cast<ushort4*>(&xbf[idx + 4]) = h1;
}

// ------- prepass 2: GPTQ dequant -> W^T bf16 [N][K] -------
// thread -> (kb, n): 8 coalesced qweight reads, one 128-B line write
__global__ __launch_bounds__(256) void dequant_wt_kernel(
    const int* __restrict__ qweight, const int* __restrict__ qzeros,
    const float* __restrict__ scales, unsigned short* __restrict__ wt)
{
    const int idx = blockIdx.x * 256 + threadIdx.x;
    const int kb = idx >> 12;            // 0..63  (block of 64 k)
    const int n  = idx & (N_DIM - 1);
    const int kr0 = kb * 8;              // first packed qweight row
    const int g = kb >> 1;               // group: (kb*64)/128
    const float sc = scales[(size_t)g * N_DIM + n];
    const int zq = qzeros[(size_t)g * (N_DIM / 8) + (n >> 3)];
    const float zf = (float)(((zq >> ((n & 7) * 4)) & 0xF) + 1);

    unsigned short* dst = &wt[(size_t)n * K_DIM + kb * 64];
#pragma unroll
    for (int i = 0; i < 8; i++) {
        const int q = qweight[(size_t)(kr0 + i) * N_DIM + n];
        bf16x8 wv;
#pragma unroll
        for (int s = 0; s < 8; s++) {
            const float w = (float)((q >> (s * 4)) & 0xF) - zf;
            wv[s] = (short)f2bf(sc * w);
        }
        *reinterpret_cast<bf16x8*>(&dst[i * 8]) = wv;
    }
}

// ---------------- main GEMM: m97 structure ----------------
// A = xbf [M][K] bf16, B = wt [N][K] bf16 (B^T layout), out fp32 + bias
#define LDSV(p) ((__attribute__((address_space(3))) void*)(p))
#define GLBV(p) ((const __attribute__((address_space(1))) void*)(p))

__global__ __launch_bounds__(256, 2) void gemm_bt_kernel(
    const unsigned short* __restrict__ xbf, const unsigned short* __restrict__ wt,
    const float* __restrict__ bias, float* __restrict__ out)
{
    __shared__ unsigned short As[BM * BK];   // [128][64] linear, 16 KB
    __shared__ unsigned short Bs[BN * BK];

    const int tid  = threadIdx.x;
    const int lane = tid & 63;
    const int wave = tid >> 6;
    const int wr = wave >> 1;
    const int wc = wave & 1;

    const int m0 = blockIdx.x * BM;
    const int n0 = blockIdx.y * BN;

    const int fr = lane & 15;
    const int fq = lane >> 4;

    f32x4 acc[4][4];
#pragma unroll
    for (int i = 0; i < 4; i++)
#pragma unroll
        for (int j = 0; j < 4; j++) acc[i][j] = (f32x4){0.f, 0.f, 0.f, 0.f};

    for (int k0 = 0; k0 < K_DIM; k0 += BK) {
        // ---- stage A,B via global_load_lds width-16 (wave-uniform LDS base + lane*16)
#pragma unroll
        for (int i = 0; i < 4; i++) {
            const int flat = (wave * 4 + i) * 64 + lane;   // chunk idx (16 B each)
            const int row = flat >> 3;                     // 8 chunks per 128-B row
            const int c   = flat & 7;
            __builtin_amdgcn_global_load_lds(
                GLBV(&xbf[(size_t)(m0 + row) * K_DIM + k0 + c * 8]),
                LDSV((char*)As + (wave * 4 + i) * 1024), 16, 0, 0);
            __builtin_amdgcn_global_load_lds(
                GLBV(&wt[(size_t)(n0 + row) * K_DIM + k0 + c * 8]),
                LDSV((char*)Bs + (wave * 4 + i) * 1024), 16, 0, 0);
        }
        __syncthreads();

        bf16x8 a_frag[2][4], b_frag[2][4];
#pragma unroll
        for (int ks = 0; ks < 2; ks++) {
            const int kb = ks * 32 + fq * 8;
#pragma unroll
            for (int mi = 0; mi < 4; mi++)
                a_frag[ks][mi] = *reinterpret_cast<const bf16x8*>(
                    &As[(wr * 64 + mi * 16 + fr) * BK + kb]);
#pragma unroll
            for (int ni = 0; ni < 4; ni++)
                b_frag[ks][ni] = *reinterpret_cast<const bf16x8*>(
                    &Bs[(wc * 64 + ni * 16 + fr) * BK + kb]);
        }
#pragma unroll
        for (int ks = 0; ks < 2; ks++)
#pragma unroll
            for (int mi = 0; mi < 4; mi++)
#pragma unroll
                for (int ni = 0; ni < 4; ni++)
                    acc[mi][ni] = __builtin_amdgcn_mfma_f32_16x16x32_bf16(
                        a_frag[ks][mi], b_frag[ks][ni], acc[mi][ni], 0, 0, 0);

        __syncthreads();
    }

    // ---- epilogue: C/D layout col=lane&15, row=(lane>>4)*4+j
#pragma unroll
    for (int ni = 0; ni < 4; ni++) {
        const int col = n0 + wc * 64 + ni * 16 + fr;
        const float bv = bias[col];
#pragma unroll
        for (int mi = 0; mi < 4; mi++) {
            const int row = m0 + wr * 64 + mi * 16 + fq * 4;
#pragma unroll
            for (int j = 0; j < 4; j++)
                out[(size_t)(row + j) * N_DIM + col] = acc[mi][ni][j] + bv;
        }
    }
}

// ---------------- fallback (round-1 fused kernel) ----------------
#define LDS_K (BK + 8)
__global__ __launch_bounds__(256, 2) void q4gemm_kernel(
    const float* __restrict__ x, const int* __restrict__ qweight,
    const int* __restrict__ qzeros, const float* __restrict__ scales,
    const float* __restrict__ bias, float* __restrict__ out)
{
    __shared__ unsigned short As[BM][LDS_K];
    __shared__ unsigned short Bs[BN][LDS_K];
    const int tid = threadIdx.x, lane = tid & 63, wave = tid >> 6;
    const int wr = wave >> 1, wc = wave & 1;
    const int m0 = blockIdx.x * BM, n0 = blockIdx.y * BN;
    const int fr = lane & 15, fq = lane >> 4, kfrag = fq << 3;
    f32x4 acc[4][4];
#pragma unroll
    for (int i = 0; i < 4; i++)
#pragma unroll
        for (int j = 0; j < 4; j++) acc[i][j] = (f32x4){0.f, 0.f, 0.f, 0.f};
    for (int k0 = 0; k0 < K_DIM; k0 += BK) {
        const int g = k0 >> 7;
#pragma unroll
        for (int i = 0; i < 8; i++) {
            int idx = tid + i * 256, row = idx >> 4, c4 = (idx & 15) << 2;
            const float4 v = *reinterpret_cast<const float4*>(
                &x[(size_t)(m0 + row) * K_DIM + k0 + c4]);
            ushort4 h; h.x = f2bf(v.x); h.y = f2bf(v.y); h.z = f2bf(v.z); h.w = f2bf(v.w);
            *reinterpret_cast<ushort4*>(&As[row][c4]) = h;
        }
#pragma unroll
        for (int i = 0; i < 4; i++) {
            int idx = tid + i * 256, krl = idx >> 7, nl = idx & 127, n = n0 + nl;
            int q = qweight[(size_t)(k0 / 8 + krl) * N_DIM + n];
            float sc = scales[(size_t)g * N_DIM + n];
            int zq = qzeros[(size_t)g * (N_DIM / 8) + (n >> 3)];
            int z = ((zq >> ((n & 7) * 4)) & 0xF) + 1;
            bf16x8 wv;
#pragma unroll
            for (int s = 0; s < 8; s++)
                wv[s] = (short)f2bf(sc * (float)(((q >> (s * 4)) & 0xF) - z));
            *reinterpret_cast<bf16x8*>(&Bs[nl][krl * 8]) = wv;
        }
        __syncthreads();
        bf16x8 a_frag[2][4], b_frag[2][4];
#pragma unroll
        for (int ks = 0; ks < 2; ks++) {
            const int kb = ks * 32 + kfrag;
#pragma unroll
            for (int mi = 0; mi < 4; mi++)
                a_frag[ks][mi] = *reinterpret_cast<const bf16x8*>(&As[wr * 64 + mi * 16 + fr][kb]);
#pragma unroll
            for (int ni = 0; ni < 4; ni++)
                b_frag[ks][ni] = *reinterpret_cast<const bf16x8*>(&Bs[wc * 64 + ni * 16 + fr][kb]);
        }
#pragma unroll
        for (int ks = 0; ks < 2; ks++)
#pragma unroll
            for (int mi = 0; mi < 4; mi++)
#pragma unroll
                for (int ni = 0; ni < 4; ni++)
                    acc[mi][ni] = __builtin_amdgcn_mfma_f32_16x16x32_bf16(
                        a_frag[ks][mi], b_frag[ks][ni], acc[mi][ni], 0, 0, 0);
        __syncthreads();
    }
#pragma unroll
    for (int ni = 0; ni < 4; ni++) {
        const int col = n0 + wc * 64 + ni * 16 + fr;
        const float bv = bias[col];
#pragma unroll
        for (int mi = 0; mi < 4; mi++)
#pragma unroll
            for (int j = 0; j < 4; j++) {
                const int row = m0 + wr * 64 + mi * 16 + fq * 4 + j;
                out[(size_t)row * N_DIM + col] = acc[mi][ni][j] + bv;
            }
    }
}

extern "C" void kernel_launch(void* const* d_in, const int* in_sizes, int n_in,
                              void* d_out, int out_size, void* d_ws, size_t ws_size,
                              hipStream_t stream) {
    const float* x       = (const float*)d_in[0];
    const int*   qweight = (const int*)d_in[1];
    const int*   qzeros  = (const int*)d_in[2];
    const float* scales  = (const float*)d_in[3];
    const float* bias    = (const float*)d_in[5];
    float*       out     = (float*)d_out;

    const size_t xbf_bytes = (size_t)TOKENS * K_DIM * 2;   // 64 MB
    const size_t wt_bytes  = (size_t)N_DIM * K_DIM * 2;    // 32 MB

    if (ws_size >= xbf_bytes + wt_bytes) {
        unsigned short* xbf = (unsigned short*)d_ws;
        unsigned short* wt  = (unsigned short*)((char*)d_ws + xbf_bytes);

        cvt_x_kernel<<<(TOKENS * K_DIM / 8 + 255) / 256, 256, 0, stream>>>(x, xbf);
        dequant_wt_kernel<<<(N_DIM * (K_DIM / 64)) / 256, 256, 0, stream>>>(
            qweight, qzeros, scales, wt);
        dim3 grid(TOKENS / BM, N_DIM / BN);
        gemm_bt_kernel<<<grid, dim3(256), 0, stream>>>(xbf, wt, bias, out);
    } else {
        dim3 grid(TOKENS / BM, N_DIM / BN);
        q4gemm_kernel<<<grid, dim3(256), 0, stream>>>(x, qweight, qzeros, scales, bias, out);
    }
}

// Round 3
// 327.703 us; speedup vs baseline: 1.5743x; 1.0975x over previous
//
#include <hip/hip_runtime.h>
#include <hip/hip_bf16.h>
#include <stdint.h>

#define K_DIM 4096
#define N_DIM 4096
#define TOKENS 8192

#define BM 128
#define BN 256
#define BK 64
#define NT (K_DIM / BK)        // 64 k-tiles
#define TILE_LDS 49152         // A 16 KB + B 32 KB per ring slot
#define A_OFF 0
#define B_OFF 16384

typedef __attribute__((ext_vector_type(8))) short bf16x8;
typedef __attribute__((ext_vector_type(4))) float f32x4;

#define LDSV(p) ((__attribute__((address_space(3))) void*)(p))
#define GLBV(p) ((const __attribute__((address_space(1))) void*)(p))
#define MEMFENCE asm volatile("" ::: "memory")

__device__ inline unsigned short f2bf(float f) {
    union { float f; unsigned u; } v; v.f = f;
    unsigned r = v.u + 0x7FFF + ((v.u >> 16) & 1);   // RNE
    return (unsigned short)(r >> 16);
}

// ---------------- prepass 1: x fp32 -> bf16 ----------------
__global__ __launch_bounds__(256) void cvt_x_kernel(const float* __restrict__ x,
                                                    unsigned short* __restrict__ xbf)
{
    size_t idx = ((size_t)blockIdx.x * 256 + threadIdx.x) * 8;
    const float4 v0 = *reinterpret_cast<const float4*>(&x[idx]);
    const float4 v1 = *reinterpret_cast<const float4*>(&x[idx + 4]);
    ushort4 h0, h1;
    h0.x = f2bf(v0.x); h0.y = f2bf(v0.y); h0.z = f2bf(v0.z); h0.w = f2bf(v0.w);
    h1.x = f2bf(v1.x); h1.y = f2bf(v1.y); h1.z = f2bf(v1.z); h1.w = f2bf(v1.w);
    *reinterpret_cast<ushort4*>(&xbf[idx]) = h0;
    *reinterpret_cast<ushort4*>(&xbf[idx + 4]) = h1;
}

// ------- prepass 2: GPTQ dequant -> W^T bf16 [N][K] -------
__global__ __launch_bounds__(256) void dequant_wt_kernel(
    const int* __restrict__ qweight, const int* __restrict__ qzeros,
    const float* __restrict__ scales, unsigned short* __restrict__ wt)
{
    const int idx = blockIdx.x * 256 + threadIdx.x;
    const int kb = idx >> 12;            // 0..63  (block of 64 k)
    const int n  = idx & (N_DIM - 1);
    const int kr0 = kb * 8;
    const int g = kb >> 1;               // group: (kb*64)/128
    const float sc = scales[(size_t)g * N_DIM + n];
    const int zq = qzeros[(size_t)g * (N_DIM / 8) + (n >> 3)];
    const float zf = (float)(((zq >> ((n & 7) * 4)) & 0xF) + 1);

    unsigned short* dst = &wt[(size_t)n * K_DIM + kb * 64];
#pragma unroll
    for (int i = 0; i < 8; i++) {
        const int q = qweight[(size_t)(kr0 + i) * N_DIM + n];
        bf16x8 wv;
#pragma unroll
        for (int s = 0; s < 8; s++) {
            const float w = (float)((q >> (s * 4)) & 0xF) - zf;
            wv[s] = (short)f2bf(sc * w);
        }
        *reinterpret_cast<bf16x8*>(&dst[i * 8]) = wv;
    }
}

// ---------------- main GEMM: 8-phase-style, ring-3, swizzled ----------------
// A = xbf [M][K] bf16, B = wt [N][K] bf16, out fp32 + bias.
// LDS logical layout per slot: A [128 rows][64 k], B [256 rows][64 k];
// stored with byte ^= ((row&7)<<4) swizzle, realized by pre-permuting the
// per-lane GLOBAL source chunk (linear LDS dest for global_load_lds).
__global__ __launch_bounds__(512, 2) void gemm_8ph_kernel(
    const unsigned short* __restrict__ xbf, const unsigned short* __restrict__ wt,
    const float* __restrict__ bias, float* __restrict__ out)
{
    __shared__ __align__(16) char lds[3 * TILE_LDS];   // 144 KB

    const int tid  = threadIdx.x;
    const int lane = tid & 63;
    const int wave = tid >> 6;
    const int wm = wave >> 2;        // 0..1  (64-row M slice)
    const int wn = wave & 3;         // 0..3  (64-col N slice)
    const int fr = lane & 15;
    const int fq = lane >> 4;

    const int m0 = blockIdx.x * BM;
    const int n0 = blockIdx.y * BN;

    // staging lane geometry: set = 64 rows x 64 k (8 KB); wave stages rows
    // wave*8..wave*8+7; lane chunk pre-swizzled so LDS-linear == swizzled store.
    const int srow = wave * 8 + (lane >> 3);             // row within set
    const int k8   = (lane & 7) ^ ((lane >> 3) & 7);     // permuted source chunk

    f32x4 acc[4][4];
#pragma unroll
    for (int i = 0; i < 4; i++)
#pragma unroll
        for (int j = 0; j < 4; j++) acc[i][j] = (f32x4){0.f, 0.f, 0.f, 0.f};

#define STAGE_SET(mat, R0, ldsoff, k0)                                         \
    __builtin_amdgcn_global_load_lds(                                          \
        GLBV((mat) + (size_t)((R0) + srow) * K_DIM + (k0) + k8 * 8),           \
        LDSV(lds + (ldsoff) + wave * 1024), 16, 0, 0)

#define STAGE_PHASE0(tt) {                                                     \
    const int _k0 = (tt) * BK; const int _o = ((tt) % 3) * TILE_LDS;           \
    STAGE_SET(xbf, m0,       _o + A_OFF,         _k0);                         \
    STAGE_SET(xbf, m0 + 64,  _o + A_OFF + 8192,  _k0);                         \
    STAGE_SET(wt,  n0,       _o + B_OFF,         _k0); }

#define STAGE_PHASE1(tt) {                                                     \
    const int _k0 = (tt) * BK; const int _o = ((tt) % 3) * TILE_LDS;           \
    STAGE_SET(wt,  n0 + 64,  _o + B_OFF + 8192,  _k0);                         \
    STAGE_SET(wt,  n0 + 128, _o + B_OFF + 16384, _k0);                         \
    STAGE_SET(wt,  n0 + 192, _o + B_OFF + 24576, _k0); }

    // swizzled fragment read: logical (row r, 16B-chunk kc) -> stored chunk kc^(r&7)
#define A_ELT(rb, r, kc) (*(const bf16x8*)(lds + (rb) * TILE_LDS + A_OFF +     \
    (r) * 128 + ((((kc) ^ ((r) & 7))) << 4)))
#define B_ELT(rb, r, kc) (*(const bf16x8*)(lds + (rb) * TILE_LDS + B_OFF +     \
    (r) * 128 + ((((kc) ^ ((r) & 7))) << 4)))

    // ---- prologue: stage tiles 0 and 1; wait tile 0 landed (6 newest may fly)
    STAGE_PHASE0(0); STAGE_PHASE1(0);
    STAGE_PHASE0(1); STAGE_PHASE1(1);
    asm volatile("s_waitcnt vmcnt(6)" ::: "memory");
    __builtin_amdgcn_s_barrier();

    bf16x8 af[4][2], bfv[2][2];

#pragma unroll 1
    for (int t = 0; t < NT; ++t) {
        const int rb = t % 3;
        const bool st = (t + 2) < NT;

        // ================= phase 0 =================
#pragma unroll
        for (int mi = 0; mi < 4; ++mi)
#pragma unroll
            for (int ks = 0; ks < 2; ++ks)
                af[mi][ks] = A_ELT(rb, wm * 64 + mi * 16 + fr, ks * 4 + fq);
#pragma unroll
        for (int ni = 0; ni < 2; ++ni)
#pragma unroll
            for (int ks = 0; ks < 2; ++ks)
                bfv[ni][ks] = B_ELT(rb, wn * 64 + ni * 16 + fr, ks * 4 + fq);
        if (st) STAGE_PHASE0(t + 2);
        MEMFENCE; __builtin_amdgcn_s_barrier();
        asm volatile("s_waitcnt lgkmcnt(0)" ::: "memory");
        __builtin_amdgcn_sched_barrier(0);
        __builtin_amdgcn_s_setprio(1);
#pragma unroll
        for (int mi = 0; mi < 4; ++mi)
#pragma unroll
            for (int ni = 0; ni < 2; ++ni)
#pragma unroll
                for (int ks = 0; ks < 2; ++ks)
                    acc[mi][ni] = __builtin_amdgcn_mfma_f32_16x16x32_bf16(
                        af[mi][ks], bfv[ni][ks], acc[mi][ni], 0, 0, 0);
        __builtin_amdgcn_s_setprio(0);
        MEMFENCE; __builtin_amdgcn_s_barrier();

        // ================= phase 1 =================
#pragma unroll
        for (int ni = 0; ni < 2; ++ni)
#pragma unroll
            for (int ks = 0; ks < 2; ++ks)
                bfv[ni][ks] = B_ELT(rb, wn * 64 + (ni + 2) * 16 + fr, ks * 4 + fq);
        if (st) STAGE_PHASE1(t + 2);
        MEMFENCE; __builtin_amdgcn_s_barrier();
        asm volatile("s_waitcnt lgkmcnt(0)" ::: "memory");
        __builtin_amdgcn_sched_barrier(0);
        __builtin_amdgcn_s_setprio(1);
#pragma unroll
        for (int mi = 0; mi < 4; ++mi)
#pragma unroll
            for (int ni = 0; ni < 2; ++ni)
#pragma unroll
                for (int ks = 0; ks < 2; ++ks)
                    acc[mi][ni + 2] = __builtin_amdgcn_mfma_f32_16x16x32_bf16(
                        af[mi][ks], bfv[ni][ks], acc[mi][ni + 2], 0, 0, 0);
        __builtin_amdgcn_s_setprio(0);
        // counted vmcnt: tile t+1 must be landed; tile t+2's 6 loads may fly
        if (t < NT - 2)      { asm volatile("s_waitcnt vmcnt(6)" ::: "memory"); }
        else if (t == NT - 2){ asm volatile("s_waitcnt vmcnt(0)" ::: "memory"); }
        if (t < NT - 1) { MEMFENCE; __builtin_amdgcn_s_barrier(); }
    }

    // ---- epilogue
#pragma unroll
    for (int ni = 0; ni < 4; ++ni) {
        const int col = n0 + wn * 64 + ni * 16 + fr;
        const float bv = bias[col];
#pragma unroll
        for (int mi = 0; mi < 4; ++mi) {
            const int row = m0 + wm * 64 + mi * 16 + fq * 4;
#pragma unroll
            for (int j = 0; j < 4; ++j)
                out[(size_t)(row + j) * N_DIM + col] = acc[mi][ni][j] + bv;
        }
    }
#undef STAGE_SET
#undef STAGE_PHASE0
#undef STAGE_PHASE1
#undef A_ELT
#undef B_ELT
}

// ---------------- fallback (round-1 fused kernel, ws too small) ----------------
#define LDS_K (BK + 8)
__global__ __launch_bounds__(256, 2) void q4gemm_kernel(
    const float* __restrict__ x, const int* __restrict__ qweight,
    const int* __restrict__ qzeros, const float* __restrict__ scales,
    const float* __restrict__ bias, float* __restrict__ out)
{
    __shared__ unsigned short As[BM][LDS_K];
    __shared__ unsigned short Bs[BM][LDS_K];
    const int tid = threadIdx.x, lane = tid & 63, wave = tid >> 6;
    const int wr = wave >> 1, wc = wave & 1;
    const int m0 = blockIdx.x * BM, nn0 = blockIdx.y * BM;
    const int fr = lane & 15, fq = lane >> 4, kfrag = fq << 3;
    f32x4 acc[4][4];
#pragma unroll
    for (int i = 0; i < 4; i++)
#pragma unroll
        for (int j = 0; j < 4; j++) acc[i][j] = (f32x4){0.f, 0.f, 0.f, 0.f};
    for (int k0 = 0; k0 < K_DIM; k0 += BK) {
        const int g = k0 >> 7;
#pragma unroll
        for (int i = 0; i < 8; i++) {
            int idx = tid + i * 256, row = idx >> 4, c4 = (idx & 15) << 2;
            const float4 v = *reinterpret_cast<const float4*>(
                &x[(size_t)(m0 + row) * K_DIM + k0 + c4]);
            ushort4 h; h.x = f2bf(v.x); h.y = f2bf(v.y); h.z = f2bf(v.z); h.w = f2bf(v.w);
            *reinterpret_cast<ushort4*>(&As[row][c4]) = h;
        }
#pragma unroll
        for (int i = 0; i < 4; i++) {
            int idx = tid + i * 256, krl = idx >> 7, nl = idx & 127, n = nn0 + nl;
            int q = qweight[(size_t)(k0 / 8 + krl) * N_DIM + n];
            float sc = scales[(size_t)g * N_DIM + n];
            int zq = qzeros[(size_t)g * (N_DIM / 8) + (n >> 3)];
            int z = ((zq >> ((n & 7) * 4)) & 0xF) + 1;
            bf16x8 wv;
#pragma unroll
            for (int s = 0; s < 8; s++)
                wv[s] = (short)f2bf(sc * (float)(((q >> (s * 4)) & 0xF) - z));
            *reinterpret_cast<bf16x8*>(&Bs[nl][krl * 8]) = wv;
        }
        __syncthreads();
        bf16x8 a_frag[2][4], b_frag[2][4];
#pragma unroll
        for (int ks = 0; ks < 2; ks++) {
            const int kb = ks * 32 + kfrag;
#pragma unroll
            for (int mi = 0; mi < 4; mi++)
                a_frag[ks][mi] = *reinterpret_cast<const bf16x8*>(&As[wr * 64 + mi * 16 + fr][kb]);
#pragma unroll
            for (int ni = 0; ni < 4; ni++)
                b_frag[ks][ni] = *reinterpret_cast<const bf16x8*>(&Bs[wc * 64 + ni * 16 + fr][kb]);
        }
#pragma unroll
        for (int ks = 0; ks < 2; ks++)
#pragma unroll
            for (int mi = 0; mi < 4; mi++)
#pragma unroll
                for (int ni = 0; ni < 4; ni++)
                    acc[mi][ni] = __builtin_amdgcn_mfma_f32_16x16x32_bf16(
                        a_frag[ks][mi], b_frag[ks][ni], acc[mi][ni], 0, 0, 0);
        __syncthreads();
    }
#pragma unroll
    for (int ni = 0; ni < 4; ni++) {
        const int col = nn0 + wc * 64 + ni * 16 + fr;
        const float bv = bias[col];
#pragma unroll
        for (int mi = 0; mi < 4; mi++)
#pragma unroll
            for (int j = 0; j < 4; j++) {
                const int row = m0 + wr * 64 + mi * 16 + fq * 4 + j;
                out[(size_t)row * N_DIM + col] = acc[mi][ni][j] + bv;
            }
    }
}

extern "C" void kernel_launch(void* const* d_in, const int* in_sizes, int n_in,
                              void* d_out, int out_size, void* d_ws, size_t ws_size,
                              hipStream_t stream) {
    const float* x       = (const float*)d_in[0];
    const int*   qweight = (const int*)d_in[1];
    const int*   qzeros  = (const int*)d_in[2];
    const float* scales  = (const float*)d_in[3];
    const float* bias    = (const float*)d_in[5];
    float*       out     = (float*)d_out;

    const size_t xbf_bytes = (size_t)TOKENS * K_DIM * 2;   // 64 MB
    const size_t wt_bytes  = (size_t)N_DIM * K_DIM * 2;    // 32 MB

    if (ws_size >= xbf_bytes + wt_bytes) {
        unsigned short* xbf = (unsigned short*)d_ws;
        unsigned short* wt  = (unsigned short*)((char*)d_ws + xbf_bytes);

        cvt_x_kernel<<<(TOKENS * K_DIM / 8 + 255) / 256, 256, 0, stream>>>(x, xbf);
        dequant_wt_kernel<<<(N_DIM * (K_DIM / 64)) / 256, 256, 0, stream>>>(
            qweight, qzeros, scales, wt);
        dim3 grid(TOKENS / BM, N_DIM / BN);
        gemm_8ph_kernel<<<grid, dim3(512), 0, stream>>>(xbf, wt, bias, out);
    } else {
        dim3 grid(TOKENS / BM, TOKENS ? (N_DIM / BM) : 1);
        q4gemm_kernel<<<dim3(TOKENS / BM, N_DIM / BM), dim3(256), 0, stream>>>(
            x, qweight, qzeros, scales, bias, out);
    }
}

// Round 4
// 325.621 us; speedup vs baseline: 1.5843x; 1.0064x over previous
//
#include <hip/hip_runtime.h>
#include <hip/hip_bf16.h>
#include <stdint.h>

#define K_DIM 4096
#define N_DIM 4096
#define TOKENS 8192

#define BM 256
#define BN 256
#define BK 64
#define NT (K_DIM / BK)        // 64 k-tiles

// LDS: 2 bufs x { A[2kh][256r][32k] | B[2kh][256c][32k] }, 16 KB units, 128 KB total
#define BUF_BYTES 65536
#define BOFS 32768
#define KH_BYTES 16384

typedef __attribute__((ext_vector_type(8))) short bf16x8;
typedef __attribute__((ext_vector_type(4))) float f32x4;

#define LDSV(p) ((__attribute__((address_space(3))) void*)(p))
#define GLBV(p) ((const __attribute__((address_space(1))) void*)(p))
#define MEMFENCE asm volatile("" ::: "memory")

__device__ inline unsigned short f2bf(float f) {
    union { float f; unsigned u; } v; v.f = f;
    unsigned r = v.u + 0x7FFF + ((v.u >> 16) & 1);   // RNE
    return (unsigned short)(r >> 16);
}

// ---------------- prepass 1: x fp32 -> bf16 ----------------
__global__ __launch_bounds__(256) void cvt_x_kernel(const float* __restrict__ x,
                                                    unsigned short* __restrict__ xbf)
{
    size_t idx = ((size_t)blockIdx.x * 256 + threadIdx.x) * 8;
    const float4 v0 = *reinterpret_cast<const float4*>(&x[idx]);
    const float4 v1 = *reinterpret_cast<const float4*>(&x[idx + 4]);
    ushort4 h0, h1;
    h0.x = f2bf(v0.x); h0.y = f2bf(v0.y); h0.z = f2bf(v0.z); h0.w = f2bf(v0.w);
    h1.x = f2bf(v1.x); h1.y = f2bf(v1.y); h1.z = f2bf(v1.z); h1.w = f2bf(v1.w);
    *reinterpret_cast<ushort4*>(&xbf[idx]) = h0;
    *reinterpret_cast<ushort4*>(&xbf[idx + 4]) = h1;
}

// ------- prepass 2: GPTQ dequant -> W^T bf16 [N][K] -------
__global__ __launch_bounds__(256) void dequant_wt_kernel(
    const int* __restrict__ qweight, const int* __restrict__ qzeros,
    const float* __restrict__ scales, unsigned short* __restrict__ wt)
{
    const int idx = blockIdx.x * 256 + threadIdx.x;
    const int kb = idx >> 12;            // 0..63  (block of 64 k)
    const int n  = idx & (N_DIM - 1);
    const int kr0 = kb * 8;
    const int g = kb >> 1;               // group: (kb*64)/128
    const float sc = scales[(size_t)g * N_DIM + n];
    const int zq = qzeros[(size_t)g * (N_DIM / 8) + (n >> 3)];
    const float zf = (float)(((zq >> ((n & 7) * 4)) & 0xF) + 1);

    unsigned short* dst = &wt[(size_t)n * K_DIM + kb * 64];
#pragma unroll
    for (int i = 0; i < 8; i++) {
        const int q = qweight[(size_t)(kr0 + i) * N_DIM + n];
        bf16x8 wv;
#pragma unroll
        for (int s = 0; s < 8; s++) {
            const float w = (float)((q >> (s * 4)) & 0xF) - zf;
            wv[s] = (short)f2bf(sc * w);
        }
        *reinterpret_cast<bf16x8*>(&dst[i * 8]) = wv;
    }
}

// ------------- main GEMM: 256x256, 8 waves, kh-split 2-phase, dbuf-2 -------------
// Unit layout (16 KB = 1024 chunks of 16B): phys chunk p(r,c) = (r>>3)*32 + c*8 + (r&7)
// (transpose within 8-row superblock -> 16-lane frag reads hit 8 bank-quads, 2-way = free).
// Store side: linear LDS dest; per-lane GLOBAL source address inverts the permutation.
__global__ __launch_bounds__(512, 2) void gemm_256_kernel(
    const unsigned short* __restrict__ xbf, const unsigned short* __restrict__ wt,
    const float* __restrict__ bias, float* __restrict__ out)
{
    __shared__ __align__(16) char lds[2 * BUF_BYTES];   // 128 KB

    const int tid  = threadIdx.x;
    const int lane = tid & 63;
    const int wave = tid >> 6;
    const int wm = wave >> 2;        // 0..1 : 128-row M slice
    const int wn = wave & 3;         // 0..3 : 64-col N slice
    const int fr = lane & 15;
    const int fq = lane >> 4;

    const int m0 = blockIdx.x * BM;
    const int n0 = blockIdx.y * BN;

    // staging: invert p(r,c): r = ((p>>5)<<3)|(p&7), c = (p>>3)&3
    const int pc0 = wave * 64 + lane;
    const int pc1 = 512 + pc0;
    const int r0 = ((pc0 >> 5) << 3) | (pc0 & 7), c0 = (pc0 >> 3) & 3;
    const int r1 = ((pc1 >> 5) << 3) | (pc1 & 7), c1 = (pc1 >> 3) & 3;

    // fragment read byte-offset within a 16 KB unit
    const int fbase = (fr >> 3) * 512 + fq * 128 + (fr & 7) * 16;
    const int abase = wm * 8192 + fbase;    // + mi*1024, mi 0..7
    const int bbase = wn * 4096 + fbase;    // + ni*1024, ni 0..3

    f32x4 acc[8][4];
#pragma unroll
    for (int i = 0; i < 8; i++)
#pragma unroll
        for (int j = 0; j < 4; j++) acc[i][j] = (f32x4){0.f, 0.f, 0.f, 0.f};

#define STAGE_UNIT(mat, R0b, ubase, kofs) do {                                  \
    __builtin_amdgcn_global_load_lds(                                           \
        GLBV((mat) + (size_t)((R0b) + r0) * K_DIM + (kofs) + c0 * 8),           \
        LDSV(lds + (ubase) + wave * 1024), 16, 0, 0);                           \
    __builtin_amdgcn_global_load_lds(                                           \
        GLBV((mat) + (size_t)((R0b) + r1) * K_DIM + (kofs) + c1 * 8),           \
        LDSV(lds + (ubase) + 8192 + wave * 1024), 16, 0, 0); } while (0)

    // per-thread issue order within STAGE_KH: A(2 calls) then B(2 calls)
#define STAGE_KH(tt, kh) do {                                                   \
    const int _nb = ((tt) & 1) * BUF_BYTES;                                     \
    const int _ko = (tt) * BK + (kh) * 32;                                      \
    STAGE_UNIT(xbf, m0, _nb + (kh) * KH_BYTES, _ko);                            \
    STAGE_UNIT(wt,  n0, _nb + BOFS + (kh) * KH_BYTES, _ko); } while (0)

    // ---- prologue: stage tile 0 (8 loads); wait kh0's 4 (A0,B0), kh1 may fly
    STAGE_KH(0, 0);
    STAGE_KH(0, 1);
    asm volatile("s_waitcnt vmcnt(4)" ::: "memory");
    __builtin_amdgcn_s_barrier();

    bf16x8 af[8], bfv[4];

#pragma unroll 1
    for (int t = 0; t < NT; ++t) {
        const int cb = (t & 1) * BUF_BYTES;
        const bool more = (t + 1) < NT;

        // ================= phase 0 (kh = 0) =================
#pragma unroll
        for (int mi = 0; mi < 8; ++mi)
            af[mi] = *reinterpret_cast<const bf16x8*>(lds + cb + abase + mi * 1024);
#pragma unroll
        for (int ni = 0; ni < 4; ++ni)
            bfv[ni] = *reinterpret_cast<const bf16x8*>(lds + cb + BOFS + bbase + ni * 1024);
        if (more) STAGE_KH(t + 1, 0);
        MEMFENCE; __builtin_amdgcn_s_barrier();
        asm volatile("s_waitcnt lgkmcnt(0)" ::: "memory");
        __builtin_amdgcn_sched_barrier(0);
        __builtin_amdgcn_s_setprio(1);
#pragma unroll
        for (int mi = 0; mi < 8; ++mi)
#pragma unroll
            for (int ni = 0; ni < 4; ++ni)
                acc[mi][ni] = __builtin_amdgcn_mfma_f32_16x16x32_bf16(
                    af[mi], bfv[ni], acc[mi][ni], 0, 0, 0);
        __builtin_amdgcn_s_setprio(0);
        // need tile t's kh1 landed (oldest 4); t+1-kh0's 4 may stay in flight
        if (more) { asm volatile("s_waitcnt vmcnt(4)" ::: "memory"); }
        else      { asm volatile("s_waitcnt vmcnt(0)" ::: "memory"); }
        MEMFENCE; __builtin_amdgcn_s_barrier();

        // ================= phase 1 (kh = 1) =================
#pragma unroll
        for (int mi = 0; mi < 8; ++mi)
            af[mi] = *reinterpret_cast<const bf16x8*>(lds + cb + KH_BYTES + abase + mi * 1024);
#pragma unroll
        for (int ni = 0; ni < 4; ++ni)
            bfv[ni] = *reinterpret_cast<const bf16x8*>(lds + cb + BOFS + KH_BYTES + bbase + ni * 1024);
        if (more) STAGE_KH(t + 1, 1);
        MEMFENCE; __builtin_amdgcn_s_barrier();
        asm volatile("s_waitcnt lgkmcnt(0)" ::: "memory");
        __builtin_amdgcn_sched_barrier(0);
        __builtin_amdgcn_s_setprio(1);
#pragma unroll
        for (int mi = 0; mi < 8; ++mi)
#pragma unroll
            for (int ni = 0; ni < 4; ++ni)
                acc[mi][ni] = __builtin_amdgcn_mfma_f32_16x16x32_bf16(
                    af[mi], bfv[ni], acc[mi][ni], 0, 0, 0);
        __builtin_amdgcn_s_setprio(0);
        if (more) {
            // need t+1-kh0 landed (oldest 4) before next phase-0 reads; kh1 may fly
            asm volatile("s_waitcnt vmcnt(4)" ::: "memory");
            MEMFENCE; __builtin_amdgcn_s_barrier();
        }
    }

    // ---- epilogue: C/D layout col=lane&15, row=(lane>>4)*4+j
#pragma unroll
    for (int ni = 0; ni < 4; ++ni) {
        const int col = n0 + wn * 64 + ni * 16 + fr;
        const float bv = bias[col];
#pragma unroll
        for (int mi = 0; mi < 8; ++mi) {
            const int row = m0 + wm * 128 + mi * 16 + fq * 4;
#pragma unroll
            for (int j = 0; j < 4; ++j)
                out[(size_t)(row + j) * N_DIM + col] = acc[mi][ni][j] + bv;
        }
    }
#undef STAGE_UNIT
#undef STAGE_KH
}

// ---------------- fallback (round-1 fused kernel, ws too small) ----------------
#define FBM 128
#define FBK 64
#define LDS_K (FBK + 8)
__global__ __launch_bounds__(256, 2) void q4gemm_kernel(
    const float* __restrict__ x, const int* __restrict__ qweight,
    const int* __restrict__ qzeros, const float* __restrict__ scales,
    const float* __restrict__ bias, float* __restrict__ out)
{
    __shared__ unsigned short As[FBM][LDS_K];
    __shared__ unsigned short Bs[FBM][LDS_K];
    const int tid = threadIdx.x, lane = tid & 63, wave = tid >> 6;
    const int wr = wave >> 1, wc = wave & 1;
    const int m0 = blockIdx.x * FBM, nn0 = blockIdx.y * FBM;
    const int fr = lane & 15, fq = lane >> 4, kfrag = fq << 3;
    f32x4 acc[4][4];
#pragma unroll
    for (int i = 0; i < 4; i++)
#pragma unroll
        for (int j = 0; j < 4; j++) acc[i][j] = (f32x4){0.f, 0.f, 0.f, 0.f};
    for (int k0 = 0; k0 < K_DIM; k0 += FBK) {
        const int g = k0 >> 7;
#pragma unroll
        for (int i = 0; i < 8; i++) {
            int idx = tid + i * 256, row = idx >> 4, c4 = (idx & 15) << 2;
            const float4 v = *reinterpret_cast<const float4*>(
                &x[(size_t)(m0 + row) * K_DIM + k0 + c4]);
            ushort4 h; h.x = f2bf(v.x); h.y = f2bf(v.y); h.z = f2bf(v.z); h.w = f2bf(v.w);
            *reinterpret_cast<ushort4*>(&As[row][c4]) = h;
        }
#pragma unroll
        for (int i = 0; i < 4; i++) {
            int idx = tid + i * 256, krl = idx >> 7, nl = idx & 127, n = nn0 + nl;
            int q = qweight[(size_t)(k0 / 8 + krl) * N_DIM + n];
            float sc = scales[(size_t)g * N_DIM + n];
            int zq = qzeros[(size_t)g * (N_DIM / 8) + (n >> 3)];
            int z = ((zq >> ((n & 7) * 4)) & 0xF) + 1;
            bf16x8 wv;
#pragma unroll
            for (int s = 0; s < 8; s++)
                wv[s] = (short)f2bf(sc * (float)(((q >> (s * 4)) & 0xF) - z));
            *reinterpret_cast<bf16x8*>(&Bs[nl][krl * 8]) = wv;
        }
        __syncthreads();
        bf16x8 a_frag[2][4], b_frag[2][4];
#pragma unroll
        for (int ks = 0; ks < 2; ks++) {
            const int kb = ks * 32 + kfrag;
#pragma unroll
            for (int mi = 0; mi < 4; mi++)
                a_frag[ks][mi] = *reinterpret_cast<const bf16x8*>(&As[wr * 64 + mi * 16 + fr][kb]);
#pragma unroll
            for (int ni = 0; ni < 4; ni++)
                b_frag[ks][ni] = *reinterpret_cast<const bf16x8*>(&Bs[wc * 64 + ni * 16 + fr][kb]);
        }
#pragma unroll
        for (int ks = 0; ks < 2; ks++)
#pragma unroll
            for (int mi = 0; mi < 4; mi++)
#pragma unroll
                for (int ni = 0; ni < 4; ni++)
                    acc[mi][ni] = __builtin_amdgcn_mfma_f32_16x16x32_bf16(
                        a_frag[ks][mi], b_frag[ks][ni], acc[mi][ni], 0, 0, 0);
        __syncthreads();
    }
#pragma unroll
    for (int ni = 0; ni < 4; ni++) {
        const int col = nn0 + wc * 64 + ni * 16 + fr;
        const float bv = bias[col];
#pragma unroll
        for (int mi = 0; mi < 4; mi++)
#pragma unroll
            for (int j = 0; j < 4; j++) {
                const int row = m0 + wr * 64 + mi * 16 + fq * 4 + j;
                out[(size_t)row * N_DIM + col] = acc[mi][ni][j] + bv;
            }
    }
}

extern "C" void kernel_launch(void* const* d_in, const int* in_sizes, int n_in,
                              void* d_out, int out_size, void* d_ws, size_t ws_size,
                              hipStream_t stream) {
    const float* x       = (const float*)d_in[0];
    const int*   qweight = (const int*)d_in[1];
    const int*   qzeros  = (const int*)d_in[2];
    const float* scales  = (const float*)d_in[3];
    const float* bias    = (const float*)d_in[5];
    float*       out     = (float*)d_out;

    const size_t xbf_bytes = (size_t)TOKENS * K_DIM * 2;   // 64 MB
    const size_t wt_bytes  = (size_t)N_DIM * K_DIM * 2;    // 32 MB

    if (ws_size >= xbf_bytes + wt_bytes) {
        unsigned short* xbf = (unsigned short*)d_ws;
        unsigned short* wt  = (unsigned short*)((char*)d_ws + xbf_bytes);

        cvt_x_kernel<<<(TOKENS * K_DIM / 8 + 255) / 256, 256, 0, stream>>>(x, xbf);
        dequant_wt_kernel<<<(N_DIM * (K_DIM / 64)) / 256, 256, 0, stream>>>(
            qweight, qzeros, scales, wt);
        dim3 grid(TOKENS / BM, N_DIM / BN);
        gemm_256_kernel<<<grid, dim3(512), 0, stream>>>(xbf, wt, bias, out);
    } else {
        q4gemm_kernel<<<dim3(TOKENS / FBM, N_DIM / FBM), dim3(256), 0, stream>>>(
            x, qweight, qzeros, scales, bias, out);
    }
}

// Round 5
// 292.860 us; speedup vs baseline: 1.7615x; 1.1119x over previous
//
#include <hip/hip_runtime.h>
#include <hip/hip_bf16.h>
#include <stdint.h>

#define K_DIM 4096
#define N_DIM 4096
#define TOKENS 8192

#define BM 256
#define BN 256
#define BK 64
#define NT (K_DIM / BK)        // 64 k-tiles

// LDS: 2 bufs x { A[256r][128B row] | B[256c][128B row] } = 2 x 64 KB.
// 16 KB units: A0(rows0-127) A1(rows128-255) B0 B1.  Row = 8 chunks of 16B,
// phys chunk = logical chunk ^ (row&7)  (conflict-free frag reads, measured r3/r4).
#define BUF_BYTES 65536
#define BOFS 32768
#define KH_BYTES 16384

typedef __attribute__((ext_vector_type(8))) short bf16x8;
typedef __attribute__((ext_vector_type(4))) float f32x4;

#define LDSV(p) ((__attribute__((address_space(3))) void*)(p))
#define GLBV(p) ((const __attribute__((address_space(1))) void*)(p))
#define MEMFENCE asm volatile("" ::: "memory")

__device__ inline unsigned short f2bf(float f) {
    union { float f; unsigned u; } v; v.f = f;
    unsigned r = v.u + 0x7FFF + ((v.u >> 16) & 1);   // RNE
    return (unsigned short)(r >> 16);
}

// ---------------- prepass 1: x fp32 -> bf16 ----------------
__global__ __launch_bounds__(256) void cvt_x_kernel(const float* __restrict__ x,
                                                    unsigned short* __restrict__ xbf)
{
    size_t idx = ((size_t)blockIdx.x * 256 + threadIdx.x) * 8;
    const float4 v0 = *reinterpret_cast<const float4*>(&x[idx]);
    const float4 v1 = *reinterpret_cast<const float4*>(&x[idx + 4]);
    ushort4 h0, h1;
    h0.x = f2bf(v0.x); h0.y = f2bf(v0.y); h0.z = f2bf(v0.z); h0.w = f2bf(v0.w);
    h1.x = f2bf(v1.x); h1.y = f2bf(v1.y); h1.z = f2bf(v1.z); h1.w = f2bf(v1.w);
    *reinterpret_cast<ushort4*>(&xbf[idx]) = h0;
    *reinterpret_cast<ushort4*>(&xbf[idx + 4]) = h1;
}

// ------- prepass 2: GPTQ dequant -> W^T bf16 [N][K] -------
__global__ __launch_bounds__(256) void dequant_wt_kernel(
    const int* __restrict__ qweight, const int* __restrict__ qzeros,
    const float* __restrict__ scales, unsigned short* __restrict__ wt)
{
    const int idx = blockIdx.x * 256 + threadIdx.x;
    const int kb = idx >> 12;            // 0..63  (block of 64 k)
    const int n  = idx & (N_DIM - 1);
    const int kr0 = kb * 8;
    const int g = kb >> 1;               // group: (kb*64)/128
    const float sc = scales[(size_t)g * N_DIM + n];
    const int zq = qzeros[(size_t)g * (N_DIM / 8) + (n >> 3)];
    const float zf = (float)(((zq >> ((n & 7) * 4)) & 0xF) + 1);

    unsigned short* dst = &wt[(size_t)n * K_DIM + kb * 64];
#pragma unroll
    for (int i = 0; i < 8; i++) {
        const int q = qweight[(size_t)(kr0 + i) * N_DIM + n];
        bf16x8 wv;
#pragma unroll
        for (int s = 0; s < 8; s++) {
            const float w = (float)((q >> (s * 4)) & 0xF) - zf;
            wv[s] = (short)f2bf(sc * w);
        }
        *reinterpret_cast<bf16x8*>(&dst[i * 8]) = wv;
    }
}

// ---------- main GEMM: 256x256, 8 waves, 4 quadrant-phases/K-tile, dbuf-2 ----------
__global__ __launch_bounds__(512, 2) void gemm_q4ph_kernel(
    const unsigned short* __restrict__ xbf, const unsigned short* __restrict__ wt,
    const float* __restrict__ bias, float* __restrict__ out)
{
    __shared__ __align__(16) char lds[2 * BUF_BYTES];   // 128 KB

    const int tid  = threadIdx.x;
    const int lane = tid & 63;
    const int wave = tid >> 6;
    const int wm = wave >> 2;        // 0..1 : 128-row M slice
    const int wn = wave & 3;         // 0..3 : 64-col N slice
    const int fr = lane & 15;
    const int fq = lane >> 4;

    const int m0 = blockIdx.x * BM;
    const int n0 = blockIdx.y * BN;

    // staging geometry: gload covers 8 rows x 8 chunks; source chunk pre-permuted
    const int srow = wave * 8 + (lane >> 3);
    const int k8   = (lane & 7) ^ ((lane >> 3) & 7);

    // fragment read offsets
    const int cx0 = ((0 * 4 + fq) ^ (fr & 7)) << 4;    // ks=0 chunk byte
    const int cx1 = ((1 * 4 + fq) ^ (fr & 7)) << 4;    // ks=1 chunk byte
    const int aoffs = wm * KH_BYTES + fr * 128;                         // + mi*2048
    const int boffs = BOFS + (wn >> 1) * KH_BYTES + ((wn & 1) * 64 + fr) * 128;  // + ni*2048

    f32x4 acc[8][4];
#pragma unroll
    for (int i = 0; i < 8; i++)
#pragma unroll
        for (int j = 0; j < 4; j++) acc[i][j] = (f32x4){0.f, 0.f, 0.f, 0.f};

#define STAGE_AU(tt, u) do {                                                    \
    const int _b = (((tt) & 1) * BUF_BYTES) + (u) * KH_BYTES;                   \
    const size_t _r = (size_t)(m0 + (u) * 128 + srow);                          \
    const int _k = (tt) * BK + k8 * 8;                                          \
    __builtin_amdgcn_global_load_lds(GLBV(xbf + _r * K_DIM + _k),               \
        LDSV(lds + _b + wave * 1024), 16, 0, 0);                                \
    __builtin_amdgcn_global_load_lds(GLBV(xbf + (_r + 64) * K_DIM + _k),        \
        LDSV(lds + _b + 8192 + wave * 1024), 16, 0, 0); } while (0)

#define STAGE_BU(tt, u) do {                                                    \
    const int _b = (((tt) & 1) * BUF_BYTES) + BOFS + (u) * KH_BYTES;            \
    const size_t _r = (size_t)(n0 + (u) * 128 + srow);                          \
    const int _k = (tt) * BK + k8 * 8;                                          \
    __builtin_amdgcn_global_load_lds(GLBV(wt + _r * K_DIM + _k),                \
        LDSV(lds + _b + wave * 1024), 16, 0, 0);                                \
    __builtin_amdgcn_global_load_lds(GLBV(wt + (_r + 64) * K_DIM + _k),         \
        LDSV(lds + _b + 8192 + wave * 1024), 16, 0, 0); } while (0)

#define PHASE_SYNC                                                              \
    MEMFENCE; __builtin_amdgcn_s_barrier();                                     \
    asm volatile("s_waitcnt lgkmcnt(0)" ::: "memory");                          \
    __builtin_amdgcn_sched_barrier(0);                                          \
    __builtin_amdgcn_s_setprio(1)

#define PHASE_END                                                               \
    __builtin_amdgcn_s_setprio(0); MEMFENCE; __builtin_amdgcn_s_barrier()

    // ---- prologue: tile0 all 4 units + tile1 A0; wait tile0 (2 may fly)
    STAGE_AU(0, 0); STAGE_AU(0, 1); STAGE_BU(0, 0); STAGE_BU(0, 1);
    STAGE_AU(1, 0);
    asm volatile("s_waitcnt vmcnt(2)" ::: "memory");
    __builtin_amdgcn_s_barrier();

    bf16x8 af[4][2], bfv[2][2];

#pragma unroll 1
    for (int t = 0; t < NT; ++t) {
        const int cb = (t & 1) * BUF_BYTES;

        // ===== phase 0 (q00): af0 + bfv0 reads, MFMA mi0-3 x ni0-1 =====
#pragma unroll
        for (int mi = 0; mi < 4; ++mi) {
            af[mi][0] = *reinterpret_cast<const bf16x8*>(lds + cb + aoffs + mi * 2048 + cx0);
            af[mi][1] = *reinterpret_cast<const bf16x8*>(lds + cb + aoffs + mi * 2048 + cx1);
        }
#pragma unroll
        for (int ni = 0; ni < 2; ++ni) {
            bfv[ni][0] = *reinterpret_cast<const bf16x8*>(lds + cb + boffs + ni * 2048 + cx0);
            bfv[ni][1] = *reinterpret_cast<const bf16x8*>(lds + cb + boffs + ni * 2048 + cx1);
        }
        if (t + 1 < NT) STAGE_AU(t + 1, 1);
        asm volatile("s_waitcnt lgkmcnt(8)" ::: "memory");   // drain-smoothing hint
        PHASE_SYNC;
#pragma unroll
        for (int mi = 0; mi < 4; ++mi)
#pragma unroll
            for (int ni = 0; ni < 2; ++ni)
#pragma unroll
                for (int ks = 0; ks < 2; ++ks)
                    acc[mi][ni] = __builtin_amdgcn_mfma_f32_16x16x32_bf16(
                        af[mi][ks], bfv[ni][ks], acc[mi][ni], 0, 0, 0);
        PHASE_END;

        // ===== phase 1 (q01): bfv1 reads (af held), MFMA mi0-3 x ni2-3 =====
#pragma unroll
        for (int ni = 0; ni < 2; ++ni) {
            bfv[ni][0] = *reinterpret_cast<const bf16x8*>(lds + cb + boffs + (ni + 2) * 2048 + cx0);
            bfv[ni][1] = *reinterpret_cast<const bf16x8*>(lds + cb + boffs + (ni + 2) * 2048 + cx1);
        }
        if (t + 1 < NT) STAGE_BU(t + 1, 0);
        PHASE_SYNC;
#pragma unroll
        for (int mi = 0; mi < 4; ++mi)
#pragma unroll
            for (int ni = 0; ni < 2; ++ni)
#pragma unroll
                for (int ks = 0; ks < 2; ++ks)
                    acc[mi][ni + 2] = __builtin_amdgcn_mfma_f32_16x16x32_bf16(
                        af[mi][ks], bfv[ni][ks], acc[mi][ni + 2], 0, 0, 0);
        PHASE_END;

        // ===== phase 2 (q11): af1 reads (bfv held), MFMA mi4-7 x ni2-3 =====
#pragma unroll
        for (int mi = 0; mi < 4; ++mi) {
            af[mi][0] = *reinterpret_cast<const bf16x8*>(lds + cb + aoffs + (mi + 4) * 2048 + cx0);
            af[mi][1] = *reinterpret_cast<const bf16x8*>(lds + cb + aoffs + (mi + 4) * 2048 + cx1);
        }
        if (t + 1 < NT) STAGE_BU(t + 1, 1);
        PHASE_SYNC;
#pragma unroll
        for (int mi = 0; mi < 4; ++mi)
#pragma unroll
            for (int ni = 0; ni < 2; ++ni)
#pragma unroll
                for (int ks = 0; ks < 2; ++ks)
                    acc[mi + 4][ni + 2] = __builtin_amdgcn_mfma_f32_16x16x32_bf16(
                        af[mi][ks], bfv[ni][ks], acc[mi + 4][ni + 2], 0, 0, 0);
        PHASE_END;

        // ===== phase 3 (q10): bfv0 re-read, MFMA mi4-7 x ni0-1; A-units of cb free =====
#pragma unroll
        for (int ni = 0; ni < 2; ++ni) {
            bfv[ni][0] = *reinterpret_cast<const bf16x8*>(lds + cb + boffs + ni * 2048 + cx0);
            bfv[ni][1] = *reinterpret_cast<const bf16x8*>(lds + cb + boffs + ni * 2048 + cx1);
        }
        if (t + 2 < NT) STAGE_AU(t + 2, 0);   // into cb's A0: safe after p2 end-barrier
        PHASE_SYNC;
#pragma unroll
        for (int mi = 0; mi < 4; ++mi)
#pragma unroll
            for (int ni = 0; ni < 2; ++ni)
#pragma unroll
                for (int ks = 0; ks < 2; ++ks)
                    acc[mi + 4][ni] = __builtin_amdgcn_mfma_f32_16x16x32_bf16(
                        af[mi][ks], bfv[ni][ks], acc[mi + 4][ni], 0, 0, 0);
        __builtin_amdgcn_s_setprio(0);
        // tile boundary: need all of tile t+1 landed; only (t+2)A0 may fly
        if (t < NT - 2)       { asm volatile("s_waitcnt vmcnt(2)" ::: "memory"); }
        else if (t == NT - 2) { asm volatile("s_waitcnt vmcnt(0)" ::: "memory"); }
        if (t < NT - 1) { MEMFENCE; __builtin_amdgcn_s_barrier(); }
    }

    // ---- epilogue: C/D layout col=lane&15, row=(lane>>4)*4+j
#pragma unroll
    for (int ni = 0; ni < 4; ++ni) {
        const int col = n0 + wn * 64 + ni * 16 + fr;
        const float bv = bias[col];
#pragma unroll
        for (int mi = 0; mi < 8; ++mi) {
            const int row = m0 + wm * 128 + mi * 16 + fq * 4;
#pragma unroll
            for (int j = 0; j < 4; ++j)
                out[(size_t)(row + j) * N_DIM + col] = acc[mi][ni][j] + bv;
        }
    }
#undef STAGE_AU
#undef STAGE_BU
#undef PHASE_SYNC
#undef PHASE_END
}

// ---------------- fallback (round-1 fused kernel, ws too small) ----------------
#define FBM 128
#define FBK 64
#define LDS_K (FBK + 8)
__global__ __launch_bounds__(256, 2) void q4gemm_kernel(
    const float* __restrict__ x, const int* __restrict__ qweight,
    const int* __restrict__ qzeros, const float* __restrict__ scales,
    const float* __restrict__ bias, float* __restrict__ out)
{
    __shared__ unsigned short As[FBM][LDS_K];
    __shared__ unsigned short Bs[FBM][LDS_K];
    const int tid = threadIdx.x, lane = tid & 63, wave = tid >> 6;
    const int wr = wave >> 1, wc = wave & 1;
    const int m0 = blockIdx.x * FBM, nn0 = blockIdx.y * FBM;
    const int fr = lane & 15, fq = lane >> 4, kfrag = fq << 3;
    f32x4 acc[4][4];
#pragma unroll
    for (int i = 0; i < 4; i++)
#pragma unroll
        for (int j = 0; j < 4; j++) acc[i][j] = (f32x4){0.f, 0.f, 0.f, 0.f};
    for (int k0 = 0; k0 < K_DIM; k0 += FBK) {
        const int g = k0 >> 7;
#pragma unroll
        for (int i = 0; i < 8; i++) {
            int idx = tid + i * 256, row = idx >> 4, c4 = (idx & 15) << 2;
            const float4 v = *reinterpret_cast<const float4*>(
                &x[(size_t)(m0 + row) * K_DIM + k0 + c4]);
            ushort4 h; h.x = f2bf(v.x); h.y = f2bf(v.y); h.z = f2bf(v.z); h.w = f2bf(v.w);
            *reinterpret_cast<ushort4*>(&As[row][c4]) = h;
        }
#pragma unroll
        for (int i = 0; i < 4; i++) {
            int idx = tid + i * 256, krl = idx >> 7, nl = idx & 127, n = nn0 + nl;
            int q = qweight[(size_t)(k0 / 8 + krl) * N_DIM + n];
            float sc = scales[(size_t)g * N_DIM + n];
            int zq = qzeros[(size_t)g * (N_DIM / 8) + (n >> 3)];
            int z = ((zq >> ((n & 7) * 4)) & 0xF) + 1;
            bf16x8 wv;
#pragma unroll
            for (int s = 0; s < 8; s++)
                wv[s] = (short)f2bf(sc * (float)(((q >> (s * 4)) & 0xF) - z));
            *reinterpret_cast<bf16x8*>(&Bs[nl][krl * 8]) = wv;
        }
        __syncthreads();
        bf16x8 a_frag[2][4], b_frag[2][4];
#pragma unroll
        for (int ks = 0; ks < 2; ks++) {
            const int kb = ks * 32 + kfrag;
#pragma unroll
            for (int mi = 0; mi < 4; mi++)
                a_frag[ks][mi] = *reinterpret_cast<const bf16x8*>(&As[wr * 64 + mi * 16 + fr][kb]);
#pragma unroll
            for (int ni = 0; ni < 4; ni++)
                b_frag[ks][ni] = *reinterpret_cast<const bf16x8*>(&Bs[wc * 64 + ni * 16 + fr][kb]);
        }
#pragma unroll
        for (int ks = 0; ks < 2; ks++)
#pragma unroll
            for (int mi = 0; mi < 4; mi++)
#pragma unroll
                for (int ni = 0; ni < 4; ni++)
                    acc[mi][ni] = __builtin_amdgcn_mfma_f32_16x16x32_bf16(
                        a_frag[ks][mi], b_frag[ks][ni], acc[mi][ni], 0, 0, 0);
        __syncthreads();
    }
#pragma unroll
    for (int ni = 0; ni < 4; ni++) {
        const int col = nn0 + wc * 64 + ni * 16 + fr;
        const float bv = bias[col];
#pragma unroll
        for (int mi = 0; mi < 4; mi++)
#pragma unroll
            for (int j = 0; j < 4; j++) {
                const int row = m0 + wr * 64 + mi * 16 + fq * 4 + j;
                out[(size_t)row * N_DIM + col] = acc[mi][ni][j] + bv;
            }
    }
}

extern "C" void kernel_launch(void* const* d_in, const int* in_sizes, int n_in,
                              void* d_out, int out_size, void* d_ws, size_t ws_size,
                              hipStream_t stream) {
    const float* x       = (const float*)d_in[0];
    const int*   qweight = (const int*)d_in[1];
    const int*   qzeros  = (const int*)d_in[2];
    const float* scales  = (const float*)d_in[3];
    const float* bias    = (const float*)d_in[5];
    float*       out     = (float*)d_out;

    const size_t xbf_bytes = (size_t)TOKENS * K_DIM * 2;   // 64 MB
    const size_t wt_bytes  = (size_t)N_DIM * K_DIM * 2;    // 32 MB

    if (ws_size >= xbf_bytes + wt_bytes) {
        unsigned short* xbf = (unsigned short*)d_ws;
        unsigned short* wt  = (unsigned short*)((char*)d_ws + xbf_bytes);

        cvt_x_kernel<<<(TOKENS * K_DIM / 8 + 255) / 256, 256, 0, stream>>>(x, xbf);
        dequant_wt_kernel<<<(N_DIM * (K_DIM / 64)) / 256, 256, 0, stream>>>(
            qweight, qzeros, scales, wt);
        dim3 grid(TOKENS / BM, N_DIM / BN);
        gemm_q4ph_kernel<<<grid, dim3(512), 0, stream>>>(xbf, wt, bias, out);
    } else {
        q4gemm_kernel<<<dim3(TOKENS / FBM, N_DIM / FBM), dim3(256), 0, stream>>>(
            x, qweight, qzeros, scales, bias, out);
    }
}

// Round 6
// 287.620 us; speedup vs baseline: 1.7936x; 1.0182x over previous
//
#include <hip/hip_runtime.h>
#include <hip/hip_bf16.h>
#include <stdint.h>

#define K_DIM 4096
#define N_DIM 4096
#define TOKENS 8192

#define BM 256
#define BN 256
#define BK 64
#define NT (K_DIM / BK)        // 64 k-tiles

// LDS: 2 bufs x { A[256r][128B row] | B[256c][128B row] } = 2 x 64 KB.
// 16 KB units: A0(rows0-127) A1(rows128-255) B0 B1.  Row = 8 chunks of 16B,
// phys chunk = logical chunk ^ (row&7)  (conflict-free frag reads, measured r3-r5).
#define BUF_BYTES 65536
#define BOFS 32768
#define KH_BYTES 16384

typedef __attribute__((ext_vector_type(8))) short bf16x8;
typedef __attribute__((ext_vector_type(4))) float f32x4;

#define LDSV(p) ((__attribute__((address_space(3))) void*)(p))
#define GLBV(p) ((const __attribute__((address_space(1))) void*)(p))
#define MEMFENCE asm volatile("" ::: "memory")

__device__ inline unsigned short f2bf(float f) {
    union { float f; unsigned u; } v; v.f = f;
    unsigned r = v.u + 0x7FFF + ((v.u >> 16) & 1);   // RNE
    return (unsigned short)(r >> 16);
}

// ---------------- prepass 1: x fp32 -> bf16 ----------------
__global__ __launch_bounds__(256) void cvt_x_kernel(const float* __restrict__ x,
                                                    unsigned short* __restrict__ xbf)
{
    size_t idx = ((size_t)blockIdx.x * 256 + threadIdx.x) * 8;
    const float4 v0 = *reinterpret_cast<const float4*>(&x[idx]);
    const float4 v1 = *reinterpret_cast<const float4*>(&x[idx + 4]);
    ushort4 h0, h1;
    h0.x = f2bf(v0.x); h0.y = f2bf(v0.y); h0.z = f2bf(v0.z); h0.w = f2bf(v0.w);
    h1.x = f2bf(v1.x); h1.y = f2bf(v1.y); h1.z = f2bf(v1.z); h1.w = f2bf(v1.w);
    *reinterpret_cast<ushort4*>(&xbf[idx]) = h0;
    *reinterpret_cast<ushort4*>(&xbf[idx + 4]) = h1;
}

// ------- prepass 2: GPTQ dequant -> W^T bf16 [N][K] -------
__global__ __launch_bounds__(256) void dequant_wt_kernel(
    const int* __restrict__ qweight, const int* __restrict__ qzeros,
    const float* __restrict__ scales, unsigned short* __restrict__ wt)
{
    const int idx = blockIdx.x * 256 + threadIdx.x;
    const int kb = idx >> 12;            // 0..63  (block of 64 k)
    const int n  = idx & (N_DIM - 1);
    const int kr0 = kb * 8;
    const int g = kb >> 1;               // group: (kb*64)/128
    const float sc = scales[(size_t)g * N_DIM + n];
    const int zq = qzeros[(size_t)g * (N_DIM / 8) + (n >> 3)];
    const float zf = (float)(((zq >> ((n & 7) * 4)) & 0xF) + 1);

    unsigned short* dst = &wt[(size_t)n * K_DIM + kb * 64];
#pragma unroll
    for (int i = 0; i < 8; i++) {
        const int q = qweight[(size_t)(kr0 + i) * N_DIM + n];
        bf16x8 wv;
#pragma unroll
        for (int s = 0; s < 8; s++) {
            const float w = (float)((q >> (s * 4)) & 0xF) - zf;
            wv[s] = (short)f2bf(sc * w);
        }
        *reinterpret_cast<bf16x8*>(&dst[i * 8]) = wv;
    }
}

// -------- main GEMM: 256x256, 8 waves, whole-tile-prefetch 2-phase, dbuf-2 --------
// Per tile: P0 {24-min ds_reads (af0,b0,b1) ; stage ALL of t+1 (8 gloads) ; bar ;
// lgkm(0) ; 32 MFMA} ; P1 {af1 reads ; bar ; lgkm(0) ; 32 MFMA} ; vmcnt(0)+bar.
// Stage targets are always the opposite buffer, whose reads were drained before
// the previous boundary barrier -> no read/write race windows at all.
__global__ __launch_bounds__(512, 2) void gemm_2ph_kernel(
    const unsigned short* __restrict__ xbf, const unsigned short* __restrict__ wt,
    const float* __restrict__ bias, float* __restrict__ out)
{
    __shared__ __align__(16) char lds[2 * BUF_BYTES];   // 128 KB

    const int tid  = threadIdx.x;
    const int lane = tid & 63;
    const int wave = tid >> 6;
    const int wm = wave >> 2;        // 0..1 : 128-row M slice
    const int wn = wave & 3;         // 0..3 : 64-col N slice
    const int fr = lane & 15;
    const int fq = lane >> 4;

    const int m0 = blockIdx.x * BM;
    const int n0 = blockIdx.y * BN;

    // staging geometry: gload covers 8 rows x 8 chunks; source chunk pre-permuted
    const int srow = wave * 8 + (lane >> 3);
    const int k8   = (lane & 7) ^ ((lane >> 3) & 7);

    // fragment read offsets
    const int cx0 = (fq ^ (fr & 7)) << 4;          // ks=0 chunk byte
    const int cx1 = ((4 + fq) ^ (fr & 7)) << 4;    // ks=1 chunk byte
    const int aoffs = wm * KH_BYTES + fr * 128;                              // + mi*2048
    const int boffs = BOFS + (wn >> 1) * KH_BYTES + ((wn & 1) * 64 + fr) * 128;  // + ni*2048

    f32x4 acc[8][4];
#pragma unroll
    for (int i = 0; i < 8; i++)
#pragma unroll
        for (int j = 0; j < 4; j++) acc[i][j] = (f32x4){0.f, 0.f, 0.f, 0.f};

#define STAGE_AU(tt, u) do {                                                    \
    const int _b = (((tt) & 1) * BUF_BYTES) + (u) * KH_BYTES;                   \
    const size_t _r = (size_t)(m0 + (u) * 128 + srow);                          \
    const int _k = (tt) * BK + k8 * 8;                                          \
    __builtin_amdgcn_global_load_lds(GLBV(xbf + _r * K_DIM + _k),               \
        LDSV(lds + _b + wave * 1024), 16, 0, 0);                                \
    __builtin_amdgcn_global_load_lds(GLBV(xbf + (_r + 64) * K_DIM + _k),        \
        LDSV(lds + _b + 8192 + wave * 1024), 16, 0, 0); } while (0)

#define STAGE_BU(tt, u) do {                                                    \
    const int _b = (((tt) & 1) * BUF_BYTES) + BOFS + (u) * KH_BYTES;            \
    const size_t _r = (size_t)(n0 + (u) * 128 + srow);                          \
    const int _k = (tt) * BK + k8 * 8;                                          \
    __builtin_amdgcn_global_load_lds(GLBV(wt + _r * K_DIM + _k),                \
        LDSV(lds + _b + wave * 1024), 16, 0, 0);                                \
    __builtin_amdgcn_global_load_lds(GLBV(wt + (_r + 64) * K_DIM + _k),         \
        LDSV(lds + _b + 8192 + wave * 1024), 16, 0, 0); } while (0)

#define STAGE_TILE(tt) do { STAGE_AU(tt, 0); STAGE_AU(tt, 1);                   \
                            STAGE_BU(tt, 0); STAGE_BU(tt, 1); } while (0)

    // ---- prologue: stage tile 0, wait, barrier
    STAGE_TILE(0);
    asm volatile("s_waitcnt vmcnt(0)" ::: "memory");
    __builtin_amdgcn_s_barrier();

    bf16x8 af[4][2], b0[2][2], b1[2][2];

#pragma unroll 1
    for (int t = 0; t < NT; ++t) {
        const int cb = (t & 1) * BUF_BYTES;

        // ===== P0: reads af0 + b0 + b1 (16), stage all of t+1 (8), 32 MFMA =====
#pragma unroll
        for (int mi = 0; mi < 4; ++mi) {
            af[mi][0] = *reinterpret_cast<const bf16x8*>(lds + cb + aoffs + mi * 2048 + cx0);
            af[mi][1] = *reinterpret_cast<const bf16x8*>(lds + cb + aoffs + mi * 2048 + cx1);
        }
#pragma unroll
        for (int ni = 0; ni < 2; ++ni) {
            b0[ni][0] = *reinterpret_cast<const bf16x8*>(lds + cb + boffs + ni * 2048 + cx0);
            b0[ni][1] = *reinterpret_cast<const bf16x8*>(lds + cb + boffs + ni * 2048 + cx1);
            b1[ni][0] = *reinterpret_cast<const bf16x8*>(lds + cb + boffs + (ni + 2) * 2048 + cx0);
            b1[ni][1] = *reinterpret_cast<const bf16x8*>(lds + cb + boffs + (ni + 2) * 2048 + cx1);
        }
        if (t + 1 < NT) STAGE_TILE(t + 1);
        MEMFENCE; __builtin_amdgcn_s_barrier();
        asm volatile("s_waitcnt lgkmcnt(0)" ::: "memory");
        __builtin_amdgcn_sched_barrier(0);
        __builtin_amdgcn_s_setprio(1);
#pragma unroll
        for (int mi = 0; mi < 4; ++mi)
#pragma unroll
            for (int ni = 0; ni < 2; ++ni)
#pragma unroll
                for (int ks = 0; ks < 2; ++ks)
                    acc[mi][ni] = __builtin_amdgcn_mfma_f32_16x16x32_bf16(
                        af[mi][ks], b0[ni][ks], acc[mi][ni], 0, 0, 0);
#pragma unroll
        for (int mi = 0; mi < 4; ++mi)
#pragma unroll
            for (int ni = 0; ni < 2; ++ni)
#pragma unroll
                for (int ks = 0; ks < 2; ++ks)
                    acc[mi][ni + 2] = __builtin_amdgcn_mfma_f32_16x16x32_bf16(
                        af[mi][ks], b1[ni][ks], acc[mi][ni + 2], 0, 0, 0);
        __builtin_amdgcn_s_setprio(0);

        // ===== P1: reads af1 (8, overwrite af regs), 32 MFMA =====
#pragma unroll
        for (int mi = 0; mi < 4; ++mi) {
            af[mi][0] = *reinterpret_cast<const bf16x8*>(lds + cb + aoffs + (mi + 4) * 2048 + cx0);
            af[mi][1] = *reinterpret_cast<const bf16x8*>(lds + cb + aoffs + (mi + 4) * 2048 + cx1);
        }
        MEMFENCE; __builtin_amdgcn_s_barrier();
        asm volatile("s_waitcnt lgkmcnt(0)" ::: "memory");
        __builtin_amdgcn_sched_barrier(0);
        __builtin_amdgcn_s_setprio(1);
#pragma unroll
        for (int mi = 0; mi < 4; ++mi)
#pragma unroll
            for (int ni = 0; ni < 2; ++ni)
#pragma unroll
                for (int ks = 0; ks < 2; ++ks)
                    acc[mi + 4][ni + 2] = __builtin_amdgcn_mfma_f32_16x16x32_bf16(
                        af[mi][ks], b1[ni][ks], acc[mi + 4][ni + 2], 0, 0, 0);
#pragma unroll
        for (int mi = 0; mi < 4; ++mi)
#pragma unroll
            for (int ni = 0; ni < 2; ++ni)
#pragma unroll
                for (int ks = 0; ks < 2; ++ks)
                    acc[mi + 4][ni] = __builtin_amdgcn_mfma_f32_16x16x32_bf16(
                        af[mi][ks], b0[ni][ks], acc[mi + 4][ni], 0, 0, 0);
        __builtin_amdgcn_s_setprio(0);

        // ===== boundary: own stages (issued ~1 full tile ago) must land =====
        if (t + 1 < NT) {
            asm volatile("s_waitcnt vmcnt(0)" ::: "memory");
            MEMFENCE; __builtin_amdgcn_s_barrier();
        }
    }

    // ---- epilogue: C/D layout col=lane&15, row=(lane>>4)*4+j
#pragma unroll
    for (int ni = 0; ni < 4; ++ni) {
        const int col = n0 + wn * 64 + ni * 16 + fr;
        const float bv = bias[col];
#pragma unroll
        for (int mi = 0; mi < 8; ++mi) {
            const int row = m0 + wm * 128 + mi * 16 + fq * 4;
#pragma unroll
            for (int j = 0; j < 4; ++j)
                out[(size_t)(row + j) * N_DIM + col] = acc[mi][ni][j] + bv;
        }
    }
#undef STAGE_AU
#undef STAGE_BU
#undef STAGE_TILE
}

// ---------------- fallback (round-1 fused kernel, ws too small) ----------------
#define FBM 128
#define FBK 64
#define LDS_K (FBK + 8)
__global__ __launch_bounds__(256, 2) void q4gemm_kernel(
    const float* __restrict__ x, const int* __restrict__ qweight,
    const int* __restrict__ qzeros, const float* __restrict__ scales,
    const float* __restrict__ bias, float* __restrict__ out)
{
    __shared__ unsigned short As[FBM][LDS_K];
    __shared__ unsigned short Bs[FBM][LDS_K];
    const int tid = threadIdx.x, lane = tid & 63, wave = tid >> 6;
    const int wr = wave >> 1, wc = wave & 1;
    const int m0 = blockIdx.x * FBM, nn0 = blockIdx.y * FBM;
    const int fr = lane & 15, fq = lane >> 4, kfrag = fq << 3;
    f32x4 acc[4][4];
#pragma unroll
    for (int i = 0; i < 4; i++)
#pragma unroll
        for (int j = 0; j < 4; j++) acc[i][j] = (f32x4){0.f, 0.f, 0.f, 0.f};
    for (int k0 = 0; k0 < K_DIM; k0 += FBK) {
        const int g = k0 >> 7;
#pragma unroll
        for (int i = 0; i < 8; i++) {
            int idx = tid + i * 256, row = idx >> 4, c4 = (idx & 15) << 2;
            const float4 v = *reinterpret_cast<const float4*>(
                &x[(size_t)(m0 + row) * K_DIM + k0 + c4]);
            ushort4 h; h.x = f2bf(v.x); h.y = f2bf(v.y); h.z = f2bf(v.z); h.w = f2bf(v.w);
            *reinterpret_cast<ushort4*>(&As[row][c4]) = h;
        }
#pragma unroll
        for (int i = 0; i < 4; i++) {
            int idx = tid + i * 256, krl = idx >> 7, nl = idx & 127, n = nn0 + nl;
            int q = qweight[(size_t)(k0 / 8 + krl) * N_DIM + n];
            float sc = scales[(size_t)g * N_DIM + n];
            int zq = qzeros[(size_t)g * (N_DIM / 8) + (n >> 3)];
            int z = ((zq >> ((n & 7) * 4)) & 0xF) + 1;
            bf16x8 wv;
#pragma unroll
            for (int s = 0; s < 8; s++)
                wv[s] = (short)f2bf(sc * (float)(((q >> (s * 4)) & 0xF) - z));
            *reinterpret_cast<bf16x8*>(&Bs[nl][krl * 8]) = wv;
        }
        __syncthreads();
        bf16x8 a_frag[2][4], b_frag[2][4];
#pragma unroll
        for (int ks = 0; ks < 2; ks++) {
            const int kb = ks * 32 + kfrag;
#pragma unroll
            for (int mi = 0; mi < 4; mi++)
                a_frag[ks][mi] = *reinterpret_cast<const bf16x8*>(&As[wr * 64 + mi * 16 + fr][kb]);
#pragma unroll
            for (int ni = 0; ni < 4; ni++)
                b_frag[ks][ni] = *reinterpret_cast<const bf16x8*>(&Bs[wc * 64 + ni * 16 + fr][kb]);
        }
#pragma unroll
        for (int ks = 0; ks < 2; ks++)
#pragma unroll
            for (int mi = 0; mi < 4; mi++)
#pragma unroll
                for (int ni = 0; ni < 4; ni++)
                    acc[mi][ni] = __builtin_amdgcn_mfma_f32_16x16x32_bf16(
                        a_frag[ks][mi], b_frag[ks][ni], acc[mi][ni], 0, 0, 0);
        __syncthreads();
    }
#pragma unroll
    for (int ni = 0; ni < 4; ni++) {
        const int col = nn0 + wc * 64 + ni * 16 + fr;
        const float bv = bias[col];
#pragma unroll
        for (int mi = 0; mi < 4; mi++)
#pragma unroll
            for (int j = 0; j < 4; j++) {
                const int row = m0 + wr * 64 + mi * 16 + fq * 4 + j;
                out[(size_t)row * N_DIM + col] = acc[mi][ni][j] + bv;
            }
    }
}

extern "C" void kernel_launch(void* const* d_in, const int* in_sizes, int n_in,
                              void* d_out, int out_size, void* d_ws, size_t ws_size,
                              hipStream_t stream) {
    const float* x       = (const float*)d_in[0];
    const int*   qweight = (const int*)d_in[1];
    const int*   qzeros  = (const int*)d_in[2];
    const float* scales  = (const float*)d_in[3];
    const float* bias    = (const float*)d_in[5];
    float*       out     = (float*)d_out;

    const size_t xbf_bytes = (size_t)TOKENS * K_DIM * 2;   // 64 MB
    const size_t wt_bytes  = (size_t)N_DIM * K_DIM * 2;    // 32 MB

    if (ws_size >= xbf_bytes + wt_bytes) {
        unsigned short* xbf = (unsigned short*)d_ws;
        unsigned short* wt  = (unsigned short*)((char*)d_ws + xbf_bytes);

        cvt_x_kernel<<<(TOKENS * K_DIM / 8 + 255) / 256, 256, 0, stream>>>(x, xbf);
        dequant_wt_kernel<<<(N_DIM * (K_DIM / 64)) / 256, 256, 0, stream>>>(
            qweight, qzeros, scales, wt);
        dim3 grid(TOKENS / BM, N_DIM / BN);
        gemm_2ph_kernel<<<grid, dim3(512), 0, stream>>>(xbf, wt, bias, out);
    } else {
        q4gemm_kernel<<<dim3(TOKENS / FBM, N_DIM / FBM), dim3(256), 0, stream>>>(
            x, qweight, qzeros, scales, bias, out);
    }
}

// Round 7
// 267.397 us; speedup vs baseline: 1.9293x; 1.0756x over previous
//
#include <hip/hip_runtime.h>
#include <hip/hip_bf16.h>
#include <stdint.h>

#define K_DIM 4096
#define N_DIM 4096
#define TOKENS 8192

#define BM 256
#define BN 256
#define BK 64
#define NT (K_DIM / BK)        // 64 k-tiles

// LDS: 2 bufs x { A[256r][128B row] | B[256c][128B row] } = 2 x 64 KB.
// 16 KB units: A0(rows0-127) A1(rows128-255) B0 B1.  Row = 8 chunks of 16B,
// phys chunk = logical chunk ^ (row&7)  (conflict-free frag reads, verified r3-r6).
#define BUF_BYTES 65536
#define BOFS 32768
#define KH_BYTES 16384

typedef __attribute__((ext_vector_type(8))) short bf16x8;
typedef __attribute__((ext_vector_type(4))) float f32x4;

#define LDSV(p) ((__attribute__((address_space(3))) void*)(p))
#define GLBV(p) ((const __attribute__((address_space(1))) void*)(p))
#define MEMFENCE asm volatile("" ::: "memory")

__device__ inline unsigned short f2bf(float f) {
    union { float f; unsigned u; } v; v.f = f;
    unsigned r = v.u + 0x7FFF + ((v.u >> 16) & 1);   // RNE
    return (unsigned short)(r >> 16);
}

// ---------------- prepass 1: x fp32 -> bf16 ----------------
__global__ __launch_bounds__(256) void cvt_x_kernel(const float* __restrict__ x,
                                                    unsigned short* __restrict__ xbf)
{
    size_t idx = ((size_t)blockIdx.x * 256 + threadIdx.x) * 8;
    const float4 v0 = *reinterpret_cast<const float4*>(&x[idx]);
    const float4 v1 = *reinterpret_cast<const float4*>(&x[idx + 4]);
    ushort4 h0, h1;
    h0.x = f2bf(v0.x); h0.y = f2bf(v0.y); h0.z = f2bf(v0.z); h0.w = f2bf(v0.w);
    h1.x = f2bf(v1.x); h1.y = f2bf(v1.y); h1.z = f2bf(v1.z); h1.w = f2bf(v1.w);
    *reinterpret_cast<ushort4*>(&xbf[idx]) = h0;
    *reinterpret_cast<ushort4*>(&xbf[idx + 4]) = h1;
}

// ------- prepass 2: GPTQ dequant -> W^T bf16 [N][K] -------
__global__ __launch_bounds__(256) void dequant_wt_kernel(
    const int* __restrict__ qweight, const int* __restrict__ qzeros,
    const float* __restrict__ scales, unsigned short* __restrict__ wt)
{
    const int idx = blockIdx.x * 256 + threadIdx.x;
    const int kb = idx >> 12;            // 0..63  (block of 64 k)
    const int n  = idx & (N_DIM - 1);
    const int kr0 = kb * 8;
    const int g = kb >> 1;               // group: (kb*64)/128
    const float sc = scales[(size_t)g * N_DIM + n];
    const int zq = qzeros[(size_t)g * (N_DIM / 8) + (n >> 3)];
    const float zf = (float)(((zq >> ((n & 7) * 4)) & 0xF) + 1);

    unsigned short* dst = &wt[(size_t)n * K_DIM + kb * 64];
#pragma unroll
    for (int i = 0; i < 8; i++) {
        const int q = qweight[(size_t)(kr0 + i) * N_DIM + n];
        bf16x8 wv;
#pragma unroll
        for (int s = 0; s < 8; s++) {
            const float w = (float)((q >> (s * 4)) & 0xF) - zf;
            wv[s] = (short)f2bf(sc * w);
        }
        *reinterpret_cast<bf16x8*>(&dst[i * 8]) = wv;
    }
}

// ----- main GEMM: 256x256, 8 waves, 1-barrier/tile software-pipelined, dbuf-2 -----
// Per tile t (cb = buf t&1):
//   S1 stage tile t+1 -> cb^1 (8 gload_lds)
//   S2 afB <- af1(t) (8 ds_reads)                       [overlaps cluster 1 issue]
//   C1: 32 MFMA  afA x b0 -> Q00, afA x b1 -> Q01
//   C2: 16 MFMA  afB x b1 -> Q11                        (b1 dies)
//   vmcnt(0) + barrier   [stages have a 48-MFMA window; all reads of cb done]
//   S7a afA <- af0(t+1), b1 <- B1(t+1) from cb^1 (12 reads)
//   C3: 16 MFMA  afB x b0 -> Q10                        (b0 dies)
//   S7b b0 <- B0(t+1) (4 reads)
// Reads of a buffer always drain (compiler lgkm before consuming MFMA) before
// the single barrier that precedes any overwrite of that buffer.
__global__ __launch_bounds__(512, 2) void gemm_sp_kernel(
    const unsigned short* __restrict__ xbf, const unsigned short* __restrict__ wt,
    const float* __restrict__ bias, float* __restrict__ out)
{
    __shared__ __align__(16) char lds[2 * BUF_BYTES];   // 128 KB

    const int tid  = threadIdx.x;
    const int lane = tid & 63;
    const int wave = tid >> 6;
    const int wm = wave >> 2;        // 0..1 : 128-row M slice
    const int wn = wave & 3;         // 0..3 : 64-col N slice
    const int fr = lane & 15;
    const int fq = lane >> 4;

    const int m0 = blockIdx.x * BM;
    const int n0 = blockIdx.y * BN;

    // staging geometry: gload covers 8 rows x 8 chunks; source chunk pre-permuted
    const int srow = wave * 8 + (lane >> 3);
    const int k8   = (lane & 7) ^ ((lane >> 3) & 7);

    // fragment read offsets
    const int cx0 = (fq ^ (fr & 7)) << 4;          // ks=0 chunk byte
    const int cx1 = ((4 + fq) ^ (fr & 7)) << 4;    // ks=1 chunk byte
    const int aoffs = wm * KH_BYTES + fr * 128;                              // + mi*2048
    const int boffs = BOFS + (wn >> 1) * KH_BYTES + ((wn & 1) * 64 + fr) * 128;  // + ni*2048

    f32x4 acc[8][4];
#pragma unroll
    for (int i = 0; i < 8; i++)
#pragma unroll
        for (int j = 0; j < 4; j++) acc[i][j] = (f32x4){0.f, 0.f, 0.f, 0.f};

#define STAGE_AU(tt, u) do {                                                    \
    const int _b = (((tt) & 1) * BUF_BYTES) + (u) * KH_BYTES;                   \
    const size_t _r = (size_t)(m0 + (u) * 128 + srow);                          \
    const int _k = (tt) * BK + k8 * 8;                                          \
    __builtin_amdgcn_global_load_lds(GLBV(xbf + _r * K_DIM + _k),               \
        LDSV(lds + _b + wave * 1024), 16, 0, 0);                                \
    __builtin_amdgcn_global_load_lds(GLBV(xbf + (_r + 64) * K_DIM + _k),        \
        LDSV(lds + _b + 8192 + wave * 1024), 16, 0, 0); } while (0)

#define STAGE_BU(tt, u) do {                                                    \
    const int _b = (((tt) & 1) * BUF_BYTES) + BOFS + (u) * KH_BYTES;            \
    const size_t _r = (size_t)(n0 + (u) * 128 + srow);                          \
    const int _k = (tt) * BK + k8 * 8;                                          \
    __builtin_amdgcn_global_load_lds(GLBV(wt + _r * K_DIM + _k),                \
        LDSV(lds + _b + wave * 1024), 16, 0, 0);                                \
    __builtin_amdgcn_global_load_lds(GLBV(wt + (_r + 64) * K_DIM + _k),         \
        LDSV(lds + _b + 8192 + wave * 1024), 16, 0, 0); } while (0)

#define STAGE_TILE(tt) do { STAGE_AU(tt, 0); STAGE_AU(tt, 1);                   \
                            STAGE_BU(tt, 0); STAGE_BU(tt, 1); } while (0)

#define LD8(off) (*reinterpret_cast<const bf16x8*>(lds + (off)))

    // ---- prologue: stage tile 0, wait, barrier, preload afA/b0/b1 of tile 0
    STAGE_TILE(0);
    asm volatile("s_waitcnt vmcnt(0)" ::: "memory");
    __builtin_amdgcn_s_barrier();

    bf16x8 afA[4][2], afB[4][2], b0[2][2], b1[2][2];
#pragma unroll
    for (int mi = 0; mi < 4; ++mi) {
        afA[mi][0] = LD8(aoffs + mi * 2048 + cx0);
        afA[mi][1] = LD8(aoffs + mi * 2048 + cx1);
    }
#pragma unroll
    for (int ni = 0; ni < 2; ++ni) {
        b0[ni][0] = LD8(boffs + ni * 2048 + cx0);
        b0[ni][1] = LD8(boffs + ni * 2048 + cx1);
        b1[ni][0] = LD8(boffs + (ni + 2) * 2048 + cx0);
        b1[ni][1] = LD8(boffs + (ni + 2) * 2048 + cx1);
    }

#pragma unroll 1
    for (int t = 0; t < NT; ++t) {
        const int cb  = (t & 1) * BUF_BYTES;
        const int cbn = cb ^ BUF_BYTES;
        const bool more = (t + 1) < NT;

        // S1: stage whole tile t+1 into the opposite buffer
        if (more) STAGE_TILE(t + 1);

        // S2: afB <- af1(t)
#pragma unroll
        for (int mi = 0; mi < 4; ++mi) {
            afB[mi][0] = LD8(cb + aoffs + (mi + 4) * 2048 + cx0);
            afB[mi][1] = LD8(cb + aoffs + (mi + 4) * 2048 + cx1);
        }
        __builtin_amdgcn_sched_barrier(0);

        // C1: afA x b0 -> Q00 ; afA x b1 -> Q01   (32 MFMA)
        __builtin_amdgcn_s_setprio(1);
#pragma unroll
        for (int mi = 0; mi < 4; ++mi)
#pragma unroll
            for (int ni = 0; ni < 2; ++ni)
#pragma unroll
                for (int ks = 0; ks < 2; ++ks)
                    acc[mi][ni] = __builtin_amdgcn_mfma_f32_16x16x32_bf16(
                        afA[mi][ks], b0[ni][ks], acc[mi][ni], 0, 0, 0);
#pragma unroll
        for (int mi = 0; mi < 4; ++mi)
#pragma unroll
            for (int ni = 0; ni < 2; ++ni)
#pragma unroll
                for (int ks = 0; ks < 2; ++ks)
                    acc[mi][ni + 2] = __builtin_amdgcn_mfma_f32_16x16x32_bf16(
                        afA[mi][ks], b1[ni][ks], acc[mi][ni + 2], 0, 0, 0);
        __builtin_amdgcn_s_setprio(0);
        __builtin_amdgcn_sched_barrier(0);

        // C2: afB x b1 -> Q11   (16 MFMA; b1 dies here)
        __builtin_amdgcn_s_setprio(1);
#pragma unroll
        for (int mi = 0; mi < 4; ++mi)
#pragma unroll
            for (int ni = 0; ni < 2; ++ni)
#pragma unroll
                for (int ks = 0; ks < 2; ++ks)
                    acc[mi + 4][ni + 2] = __builtin_amdgcn_mfma_f32_16x16x32_bf16(
                        afB[mi][ks], b1[ni][ks], acc[mi + 4][ni + 2], 0, 0, 0);
        __builtin_amdgcn_s_setprio(0);

        // boundary: own stages (issued a 48-MFMA window ago) land; sync all waves
        asm volatile("s_waitcnt vmcnt(0)" ::: "memory");
        MEMFENCE; __builtin_amdgcn_s_barrier(); MEMFENCE;

        // S7a: afA <- af0(t+1), b1 <- B1(t+1)   (12 reads, overlap C3)
        if (more) {
#pragma unroll
            for (int mi = 0; mi < 4; ++mi) {
                afA[mi][0] = LD8(cbn + aoffs + mi * 2048 + cx0);
                afA[mi][1] = LD8(cbn + aoffs + mi * 2048 + cx1);
            }
#pragma unroll
            for (int ni = 0; ni < 2; ++ni) {
                b1[ni][0] = LD8(cbn + boffs + (ni + 2) * 2048 + cx0);
                b1[ni][1] = LD8(cbn + boffs + (ni + 2) * 2048 + cx1);
            }
        }
        __builtin_amdgcn_sched_barrier(0);

        // C3: afB x b0 -> Q10   (16 MFMA; b0 dies here)
        __builtin_amdgcn_s_setprio(1);
#pragma unroll
        for (int mi = 0; mi < 4; ++mi)
#pragma unroll
            for (int ni = 0; ni < 2; ++ni)
#pragma unroll
                for (int ks = 0; ks < 2; ++ks)
                    acc[mi + 4][ni] = __builtin_amdgcn_mfma_f32_16x16x32_bf16(
                        afB[mi][ks], b0[ni][ks], acc[mi + 4][ni], 0, 0, 0);
        __builtin_amdgcn_s_setprio(0);

        // S7b: b0 <- B0(t+1)   (4 late reads; drained by compiler wait at next C1)
        if (more) {
#pragma unroll
            for (int ni = 0; ni < 2; ++ni) {
                b0[ni][0] = LD8(cbn + boffs + ni * 2048 + cx0);
                b0[ni][1] = LD8(cbn + boffs + ni * 2048 + cx1);
            }
        }
    }

    // ---- epilogue: C/D layout col=lane&15, row=(lane>>4)*4+j
#pragma unroll
    for (int ni = 0; ni < 4; ++ni) {
        const int col = n0 + wn * 64 + ni * 16 + fr;
        const float bv = bias[col];
#pragma unroll
        for (int mi = 0; mi < 8; ++mi) {
            const int row = m0 + wm * 128 + mi * 16 + fq * 4;
#pragma unroll
            for (int j = 0; j < 4; ++j)
                out[(size_t)(row + j) * N_DIM + col] = acc[mi][ni][j] + bv;
        }
    }
#undef STAGE_AU
#undef STAGE_BU
#undef STAGE_TILE
#undef LD8
}

// ---------------- fallback (round-1 fused kernel, ws too small) ----------------
#define FBM 128
#define FBK 64
#define LDS_K (FBK + 8)
__global__ __launch_bounds__(256, 2) void q4gemm_kernel(
    const float* __restrict__ x, const int* __restrict__ qweight,
    const int* __restrict__ qzeros, const float* __restrict__ scales,
    const float* __restrict__ bias, float* __restrict__ out)
{
    __shared__ unsigned short As[FBM][LDS_K];
    __shared__ unsigned short Bs[FBM][LDS_K];
    const int tid = threadIdx.x, lane = tid & 63, wave = tid >> 6;
    const int wr = wave >> 1, wc = wave & 1;
    const int m0 = blockIdx.x * FBM, nn0 = blockIdx.y * FBM;
    const int fr = lane & 15, fq = lane >> 4, kfrag = fq << 3;
    f32x4 acc[4][4];
#pragma unroll
    for (int i = 0; i < 4; i++)
#pragma unroll
        for (int j = 0; j < 4; j++) acc[i][j] = (f32x4){0.f, 0.f, 0.f, 0.f};
    for (int k0 = 0; k0 < K_DIM; k0 += FBK) {
        const int g = k0 >> 7;
#pragma unroll
        for (int i = 0; i < 8; i++) {
            int idx = tid + i * 256, row = idx >> 4, c4 = (idx & 15) << 2;
            const float4 v = *reinterpret_cast<const float4*>(
                &x[(size_t)(m0 + row) * K_DIM + k0 + c4]);
            ushort4 h; h.x = f2bf(v.x); h.y = f2bf(v.y); h.z = f2bf(v.z); h.w = f2bf(v.w);
            *reinterpret_cast<ushort4*>(&As[row][c4]) = h;
        }
#pragma unroll
        for (int i = 0; i < 4; i++) {
            int idx = tid + i * 256, krl = idx >> 7, nl = idx & 127, n = nn0 + nl;
            int q = qweight[(size_t)(k0 / 8 + krl) * N_DIM + n];
            float sc = scales[(size_t)g * N_DIM + n];
            int zq = qzeros[(size_t)g * (N_DIM / 8) + (n >> 3)];
            int z = ((zq >> ((n & 7) * 4)) & 0xF) + 1;
            bf16x8 wv;
#pragma unroll
            for (int s = 0; s < 8; s++)
                wv[s] = (short)f2bf(sc * (float)(((q >> (s * 4)) & 0xF) - z));
            *reinterpret_cast<bf16x8*>(&Bs[nl][krl * 8]) = wv;
        }
        __syncthreads();
        bf16x8 a_frag[2][4], b_frag[2][4];
#pragma unroll
        for (int ks = 0; ks < 2; ks++) {
            const int kb = ks * 32 + kfrag;
#pragma unroll
            for (int mi = 0; mi < 4; mi++)
                a_frag[ks][mi] = *reinterpret_cast<const bf16x8*>(&As[wr * 64 + mi * 16 + fr][kb]);
#pragma unroll
            for (int ni = 0; ni < 4; ni++)
                b_frag[ks][ni] = *reinterpret_cast<const bf16x8*>(&Bs[wc * 64 + ni * 16 + fr][kb]);
        }
#pragma unroll
        for (int ks = 0; ks < 2; ks++)
#pragma unroll
            for (int mi = 0; mi < 4; mi++)
#pragma unroll
                for (int ni = 0; ni < 4; ni++)
                    acc[mi][ni] = __builtin_amdgcn_mfma_f32_16x16x32_bf16(
                        a_frag[ks][mi], b_frag[ks][ni], acc[mi][ni], 0, 0, 0);
        __syncthreads();
    }
#pragma unroll
    for (int ni = 0; ni < 4; ni++) {
        const int col = nn0 + wc * 64 + ni * 16 + fr;
        const float bv = bias[col];
#pragma unroll
        for (int mi = 0; mi < 4; mi++)
#pragma unroll
            for (int j = 0; j < 4; j++) {
                const int row = m0 + wr * 64 + mi * 16 + fq * 4 + j;
                out[(size_t)row * N_DIM + col] = acc[mi][ni][j] + bv;
            }
    }
}

extern "C" void kernel_launch(void* const* d_in, const int* in_sizes, int n_in,
                              void* d_out, int out_size, void* d_ws, size_t ws_size,
                              hipStream_t stream) {
    const float* x       = (const float*)d_in[0];
    const int*   qweight = (const int*)d_in[1];
    const int*   qzeros  = (const int*)d_in[2];
    const float* scales  = (const float*)d_in[3];
    const float* bias    = (const float*)d_in[5];
    float*       out     = (float*)d_out;

    const size_t xbf_bytes = (size_t)TOKENS * K_DIM * 2;   // 64 MB
    const size_t wt_bytes  = (size_t)N_DIM * K_DIM * 2;    // 32 MB

    if (ws_size >= xbf_bytes + wt_bytes) {
        unsigned short* xbf = (unsigned short*)d_ws;
        unsigned short* wt  = (unsigned short*)((char*)d_ws + xbf_bytes);

        cvt_x_kernel<<<(TOKENS * K_DIM / 8 + 255) / 256, 256, 0, stream>>>(x, xbf);
        dequant_wt_kernel<<<(N_DIM * (K_DIM / 64)) / 256, 256, 0, stream>>>(
            qweight, qzeros, scales, wt);
        dim3 grid(TOKENS / BM, N_DIM / BN);
        gemm_sp_kernel<<<grid, dim3(512), 0, stream>>>(xbf, wt, bias, out);
    } else {
        q4gemm_kernel<<<dim3(TOKENS / FBM, N_DIM / FBM), dim3(256), 0, stream>>>(
            x, qweight, qzeros, scales, bias, out);
    }
}